// Round 10
// baseline (817.324 us; speedup 1.0000x reference)
//
#include <hip/hip_runtime.h>

#define TPB 256

typedef __attribute__((ext_vector_type(4))) float f32x4;
typedef __attribute__((ext_vector_type(8))) short bf16x8;

// ---------------------------------------------------------------------------
// Weight transform fp32: src OIHW (iohw=0) or IOHW (iohw=1) -> [tap][ci][co]
// ---------------------------------------------------------------------------
__global__ void wtrans_kernel(const float* __restrict__ src, float* __restrict__ dst,
                              int CIN, int COUT, int taps, int iohw) {
    int idx = blockIdx.x * TPB + threadIdx.x;
    int tot = CIN * COUT * taps;
    if (idx >= tot) return;
    int co = idx % COUT;
    int ci = (idx / COUT) % CIN;
    int tap = idx / (COUT * CIN);
    float v = iohw ? src[(ci * COUT + co) * taps + tap]
                   : src[(co * CIN + ci) * taps + tap];
    dst[idx] = v;
}

// ---------------------------------------------------------------------------
__device__ __forceinline__ unsigned bf16_rne(float v) {
    unsigned u = __float_as_uint(v);
    return (u + 0x7FFFu + ((u >> 16) & 1u)) >> 16;
}

// ---------------------------------------------------------------------------
// Weight transform bf16-split: fp32 -> hi plane [tap][co][ci], lo at +PL.
// ---------------------------------------------------------------------------
__global__ void wtrans_bf16_kernel(const float* __restrict__ src, short* __restrict__ dst,
                                   int CIN, int COUT, int taps, int iohw, int PL) {
    int idx = blockIdx.x * TPB + threadIdx.x;
    int tot = CIN * COUT * taps;
    if (idx >= tot) return;
    int ci = idx % CIN;
    int co = (idx / CIN) % COUT;
    int tap = idx / (CIN * COUT);
    float v = iohw ? src[(ci * COUT + co) * taps + tap]
                   : src[(co * CIN + ci) * taps + tap];
    unsigned h = bf16_rne(v);
    float rem = v - __uint_as_float(h << 16);
    dst[idx] = (short)h;
    dst[idx + PL] = (short)bf16_rne(rem);
}

// ---------------------------------------------------------------------------
// wd2 weights -> bf16 [cls(4)][tap(4)][co(16 pad from 3)][ci(64)]
// ---------------------------------------------------------------------------
__global__ void wtrans_wd2_kernel(const float* __restrict__ src, short* __restrict__ dst) {
    int idx = blockIdx.x * TPB + threadIdx.x;
    if (idx >= 16384) return;
    int ci  = idx & 63;
    int co  = (idx >> 6) & 15;
    int tap = (idx >> 10) & 3;
    int cls = idx >> 12;
    int py = cls >> 1, px = cls & 1;
    int jj = tap >> 1, ii = tap & 1;
    int ky = (1 - py) + 2 * jj;
    int kx = (1 - px) + 2 * ii;
    float v = (co < 3) ? src[(ci * 3 + co) * 16 + ky * 4 + kx] : 0.f;
    dst[idx] = (short)bf16_rne(v);
}

// ---------------------------------------------------------------------------
// embed [64,512] fp32 -> transposed split bf16 [n=512][k=64], hi | lo planes.
// ---------------------------------------------------------------------------
__global__ void etrans_kernel(const float* __restrict__ et, const float* __restrict__ eb,
                              short* __restrict__ ETt, short* __restrict__ ETb) {
    int idx = blockIdx.x * TPB + threadIdx.x;
    if (idx >= 65536) return;
    const float* src = (idx < 32768) ? et : eb;
    short* dst = (idx < 32768) ? ETt : ETb;
    int i = idx & 32767;
    int k = i & 63;
    int n = i >> 6;
    float v = src[k * 512 + n];
    unsigned h = bf16_rne(v);
    float rem = v - __uint_as_float(h << 16);
    dst[i] = (short)h;
    dst[i + 32768] = (short)bf16_rne(rem);
}

// ---------------------------------------------------------------------------
__device__ __forceinline__ void cvt_split2(float a, float b, unsigned& hw, unsigned& lw) {
    unsigned ha = bf16_rne(a), hb = bf16_rne(b);
    float ra = a - __uint_as_float(ha << 16);
    float rb = b - __uint_as_float(hb << 16);
    hw = ha | (hb << 16);
    lw = bf16_rne(ra) | (bf16_rne(rb) << 16);
}
__device__ __forceinline__ unsigned cvt_pk(float a, float b) {
    return bf16_rne(a) | (bf16_rne(b) << 16);
}

// ---------------------------------------------------------------------------
// Swizzled LDS index: 16B group g (8 shorts) of row stored at g^((row>>3)&3)
// within its 32-short chunk.  Breaks the period-8 bank collision of strided
// row bases while keeping 16B alignment for b128 ops.
// ---------------------------------------------------------------------------
template<int ST>
__device__ __forceinline__ int lidx(int row, int koff) {
    int g  = (koff >> 3) & 3;
    int kc = koff & ~31;
    int gs = g ^ ((row >> 3) & 3);
    return row * ST + kc + (gs << 3);
}

// ---------------------------------------------------------------------------
// MFMA implicit-GEMM conv.  bf16(-split) compute; staging is uint4 copy when
// INBF=1.  MODE 0: 4x4 s2 p1 conv.  MODE 1: convT (4 parity classes).
// MODE 2: 1x1.  OUTB: 0 = fp32; 2 = plain bf16; 3 = split bf16.
// KR: K per barrier round.  NSP: co-split factor (block handles COUT/NSP).
// ---------------------------------------------------------------------------
template<int MODE, int CIN, int COUT, int SPLIT, int RELU,
         int IH, int IW, int OH, int OW, int R, int INBF, int OUTB, int KR, int NSP>
__global__ __launch_bounds__(256) void mfma_conv(
    const void* __restrict__ inv, const short* __restrict__ Wb,
    const float* __restrict__ bias, float* __restrict__ outp,
    short* __restrict__ outb) {
    constexpr int TAPS = (MODE == 0) ? 16 : (MODE == 1 ? 4 : 1);
    constexpr int CW = (MODE == 1) ? OW / 2 : OW;
    constexpr int CH = (MODE == 1) ? OH / 2 : OH;
    constexpr int NCOUT = COUT / NSP;           // logical cout per block
    constexpr int NRND = CIN / KR;
    constexpr int KC = KR / 32;
    constexpr int ST = KR + 8;
    constexpr int MTc = (NCOUT == 128) ? 4 : 2;
    constexpr long PLW = (long)TAPS * COUT * CIN;
    constexpr long APL_IN  = 16L * IH * IW * CIN;
    constexpr long APL_OUT = 16L * OH * OW * COUT;
    constexpr int NU4A = KR / 16;
    constexpr int TPR  = 256 / NCOUT;
    constexpr int SPT  = KR / TPR;
    constexpr int NU4B = SPT / 8;

    __shared__ short Ah[128 * ST];
    __shared__ short Al[SPLIT ? 128 * ST : 8];
    __shared__ short Bh[NCOUT * ST];
    __shared__ short Bl[SPLIT ? NCOUT * ST : 8];

    int bx = blockIdx.x;
    int co_off = 0;
    if (NSP == 2) { co_off = (bx & 1) * NCOUT; bx >>= 1; }
    int ry = 0, rx = 0;
    if (MODE == 1) { int c = bx & 3; ry = c >> 1; rx = c & 1; bx >>= 2; }
    const int y0 = (bx % (CH / R)) * R;
    const int n  = bx / (CH / R);

    const int tid = threadIdx.x;
    const int p   = tid >> 1;
    const int akb = (tid & 1) * (KR / 2);
    const int rr = p / CW, xx = p % CW;
    const int bco = tid / TPR;
    const int bk  = (tid % TPR) * SPT;
    const int lane = tid & 63, wv = tid >> 6;
    const int quad = lane >> 4, l16 = lane & 15;
    const int mbase = (NCOUT == 128) ? (wv & 1) * 64 : wv * 32;
    const int nbase = (NCOUT == 128) ? (wv >> 1) * 64 : 0;

    f32x4 acc[MTc][4];
#pragma unroll
    for (int mt = 0; mt < MTc; ++mt)
#pragma unroll
        for (int nt = 0; nt < 4; ++nt) acc[mt][nt] = f32x4{0.f, 0.f, 0.f, 0.f};

#pragma unroll 1
    for (int tap = 0; tap < TAPS; ++tap) {
        int iy, ix, wt;
        if (MODE == 0) {
            int ky = tap >> 2, kx = tap & 3;
            iy = 2 * (y0 + rr) - 1 + ky;
            ix = 2 * xx - 1 + kx;
            wt = tap;
        } else if (MODE == 1) {
            int jj = tap >> 1, ii = tap & 1;
            iy = (y0 + rr) + ry - jj;
            ix = xx + rx - ii;
            wt = ((1 - ry) + 2 * jj) * 4 + ((1 - rx) + 2 * ii);
        } else {
            iy = y0 + rr; ix = xx; wt = 0;
        }
        const bool av = (MODE == 2) ||
                        ((iy >= 0) && (iy < IH) && (ix >= 0) && (ix < IW));
        const long abase = ((long)(n * IH + iy) * IW + ix) * CIN + akb;

#pragma unroll 1
        for (int ko = 0; ko < NRND; ++ko) {
            __syncthreads();
            if constexpr (INBF) {
                const short* sb = (const short*)inv + abase + ko * KR;
#pragma unroll
                for (int u = 0; u < NU4A; ++u) {
                    uint4 h = av ? *(const uint4*)(sb + 8 * u) : make_uint4(0, 0, 0, 0);
                    *(uint4*)&Ah[lidx<ST>(p, akb + 8 * u)] = h;
                }
                if constexpr (SPLIT) {
#pragma unroll
                    for (int u = 0; u < NU4A; ++u) {
                        uint4 l = av ? *(const uint4*)(sb + APL_IN + 8 * u) : make_uint4(0, 0, 0, 0);
                        *(uint4*)&Al[lidx<ST>(p, akb + 8 * u)] = l;
                    }
                }
            } else {
                const float* sp = (const float*)inv + abase + ko * KR;
#pragma unroll
                for (int u = 0; u < NU4A; ++u) {
                    float4 f0, f1;
                    if (av) { f0 = *(const float4*)(sp + 8 * u); f1 = *(const float4*)(sp + 8 * u + 4); }
                    else { f0.x=f0.y=f0.z=f0.w=0.f; f1 = f0; }
                    unsigned h0, l0, h1, l1, h2, l2, h3, l3;
                    cvt_split2(f0.x, f0.y, h0, l0); cvt_split2(f0.z, f0.w, h1, l1);
                    cvt_split2(f1.x, f1.y, h2, l2); cvt_split2(f1.z, f1.w, h3, l3);
                    *(uint4*)&Ah[lidx<ST>(p, akb + 8 * u)] = make_uint4(h0, h1, h2, h3);
                    if constexpr (SPLIT)
                        *(uint4*)&Al[lidx<ST>(p, akb + 8 * u)] = make_uint4(l0, l1, l2, l3);
                }
            }
            {
                const short* wr = Wb + ((long)wt * COUT + co_off + bco) * CIN + ko * KR + bk;
#pragma unroll
                for (int u = 0; u < NU4B; ++u) {
                    *(uint4*)&Bh[lidx<ST>(bco, bk + 8 * u)] = *(const uint4*)(wr + 8 * u);
                    if constexpr (SPLIT)
                        *(uint4*)&Bl[lidx<ST>(bco, bk + 8 * u)] = *(const uint4*)(wr + PLW + 8 * u);
                }
            }
            __syncthreads();
#pragma unroll
            for (int kc = 0; kc < KC; ++kc) {
                bf16x8 ahf[MTc], alf[SPLIT ? MTc : 1];
#pragma unroll
                for (int mt = 0; mt < MTc; ++mt) {
                    int mrow = mbase + mt * 16 + l16;
                    ahf[mt] = *(const bf16x8*)&Ah[lidx<ST>(mrow, kc * 32 + quad * 8)];
                    if constexpr (SPLIT)
                        alf[mt] = *(const bf16x8*)&Al[lidx<ST>(mrow, kc * 32 + quad * 8)];
                }
#pragma unroll
                for (int nt = 0; nt < 4; ++nt) {
                    int nrow = nbase + nt * 16 + l16;
                    bf16x8 bhf = *(const bf16x8*)&Bh[lidx<ST>(nrow, kc * 32 + quad * 8)];
#pragma unroll
                    for (int mt = 0; mt < MTc; ++mt)
                        acc[mt][nt] = __builtin_amdgcn_mfma_f32_16x16x32_bf16(ahf[mt], bhf, acc[mt][nt], 0, 0, 0);
                    if constexpr (SPLIT) {
                        bf16x8 blf = *(const bf16x8*)&Bl[lidx<ST>(nrow, kc * 32 + quad * 8)];
#pragma unroll
                        for (int mt = 0; mt < MTc; ++mt) {
                            acc[mt][nt] = __builtin_amdgcn_mfma_f32_16x16x32_bf16(alf[mt], bhf, acc[mt][nt], 0, 0, 0);
                            acc[mt][nt] = __builtin_amdgcn_mfma_f32_16x16x32_bf16(ahf[mt], blf, acc[mt][nt], 0, 0, 0);
                        }
                    }
                }
            }
        }
    }
#pragma unroll
    for (int mt = 0; mt < MTc; ++mt)
#pragma unroll
        for (int nt = 0; nt < 4; ++nt) {
            int co = co_off + nbase + nt * 16 + l16;
            float bv = bias[co];
#pragma unroll
            for (int r = 0; r < 4; ++r) {
                int pl = mbase + mt * 16 + quad * 4 + r;
                int rr2 = pl / CW, x2 = pl % CW;
                int oy, ox;
                if (MODE == 1) { oy = 2 * (y0 + rr2) + ry; ox = 2 * x2 + rx; }
                else           { oy = y0 + rr2; ox = x2; }
                float vv = acc[mt][nt][r] + bv;
                if (RELU) vv = fmaxf(vv, 0.f);
                long oidx = ((long)(n * OH + oy) * OW + ox) * COUT + co;
                if constexpr (OUTB == 0) outp[oidx] = vv;
                if constexpr (OUTB == 3) {
                    unsigned hh = bf16_rne(vv);
                    outb[oidx] = (short)hh;
                    outb[oidx + APL_OUT] = (short)bf16_rne(vv - __uint_as_float(hh << 16));
                }
                if constexpr (OUTB == 2) outb[oidx] = (short)bf16_rne(vv);
            }
        }
}

// ---------------------------------------------------------------------------
// Generic fp32 tiled conv-as-GEMM (wdt / wqb — id-critical exact path).
// ---------------------------------------------------------------------------
template<int MODE, int CIN, int COUT, int BM, int RELU, int IH, int IW, int OH, int OW>
__global__ __launch_bounds__(256) void conv_gemm(
    const float* __restrict__ in, const float* __restrict__ Wt,
    const float* __restrict__ bias, float* __restrict__ out) {
    constexpr int CHUNK  = 64;
    constexpr int NCH    = CIN / CHUNK;
    constexpr int CO_PER = (COUT == 128) ? 4 : 2;
    constexpr int PX_PER = BM / 8;
    constexpr int TAPS   = (MODE == 0) ? 16 : (MODE == 1 ? 4 : 1);
    __shared__ float As[CHUNK * BM];
    __shared__ float Bs[CHUNK * COUT];
    const int tid = threadIdx.x;
    const int bx  = blockIdx.x;
    int n, oy, ox0 = 0, par = 0;
    if (MODE == 1) {
        par = bx & 1;
        oy  = (bx >> 1) % OH;
        n   = bx / (2 * OH);
    } else {
        constexpr int SPR = OW / BM;
        int s = bx % SPR;
        oy = (bx / SPR) % OH;
        n  = bx / (SPR * OH);
        ox0 = s * BM;
    }
    const int cog = tid & 31;
    const int pxg = tid >> 5;
    const int co0 = cog * CO_PER, px0 = pxg * PX_PER;
    float acc[PX_PER][CO_PER];
#pragma unroll
    for (int q = 0; q < PX_PER; ++q)
#pragma unroll
        for (int j = 0; j < CO_PER; ++j) acc[q][j] = 0.f;
    constexpr int TPX  = 256 / BM;
    constexpr int CIPT = CHUNK / TPX;
    const int spx  = tid / TPX;
    const int sci0 = (tid % TPX) * CIPT;
    const int py   = oy & 1;

#pragma unroll 1
    for (int tap = 0; tap < TAPS; ++tap) {
        int iy, twi, sx;
        if (MODE == 0) {
            int ky = tap >> 2, kx = tap & 3;
            iy  = 2 * oy - 1 + ky;
            sx  = 2 * (ox0 + spx) - 1 + kx;
            twi = tap;
        } else if (MODE == 1) {
            int jj = tap >> 1, ii = tap & 1;
            iy  = ((oy + 1) >> 1) - jj;
            sx  = spx + par - ii;
            twi = ((1 - py) + 2 * jj) * 4 + ((1 - par) + 2 * ii);
        } else {
            iy = oy; sx = ox0 + spx; twi = 0;
        }
        const bool pxv = (iy >= 0) && (iy < IH) && (sx >= 0) && (sx < IW);
        const float* srcp = in + (((long)n * IH + iy) * IW + sx) * CIN + sci0;
#pragma unroll 1
        for (int cb = 0; cb < NCH; ++cb) {
            __syncthreads();
            float4 tmp[CIPT / 4];
#pragma unroll
            for (int t4 = 0; t4 < CIPT / 4; ++t4) {
                if (pxv) tmp[t4] = *(const float4*)(srcp + cb * CHUNK + 4 * t4);
                else { tmp[t4].x = 0.f; tmp[t4].y = 0.f; tmp[t4].z = 0.f; tmp[t4].w = 0.f; }
            }
#pragma unroll
            for (int t4 = 0; t4 < CIPT / 4; ++t4) {
                As[(sci0 + 4 * t4 + 0) * BM + spx] = tmp[t4].x;
                As[(sci0 + 4 * t4 + 1) * BM + spx] = tmp[t4].y;
                As[(sci0 + 4 * t4 + 2) * BM + spx] = tmp[t4].z;
                As[(sci0 + 4 * t4 + 3) * BM + spx] = tmp[t4].w;
            }
            {
                const float4* wsrc = (const float4*)(Wt + ((long)twi * CIN + cb * CHUNK) * COUT);
#pragma unroll
                for (int t4 = 0; t4 < (CHUNK * COUT) / 1024; ++t4)
                    ((float4*)Bs)[tid + 256 * t4] = wsrc[tid + 256 * t4];
            }
            __syncthreads();
#pragma unroll 4
            for (int k = 0; k < CHUNK; ++k) {
                float a[PX_PER];
#pragma unroll
                for (int t4 = 0; t4 < PX_PER / 4; ++t4)
                    *(float4*)&a[4 * t4] = *(const float4*)&As[k * BM + px0 + 4 * t4];
                if constexpr (CO_PER == 4) {
                    float4 b = *(const float4*)&Bs[k * COUT + co0];
#pragma unroll
                    for (int q = 0; q < PX_PER; ++q) {
                        acc[q][0] = fmaf(a[q], b.x, acc[q][0]);
                        acc[q][1] = fmaf(a[q], b.y, acc[q][1]);
                        acc[q][2] = fmaf(a[q], b.z, acc[q][2]);
                        acc[q][3] = fmaf(a[q], b.w, acc[q][3]);
                    }
                } else {
                    float2 b = *(const float2*)&Bs[k * COUT + co0];
#pragma unroll
                    for (int q = 0; q < PX_PER; ++q) {
                        acc[q][0] = fmaf(a[q], b.x, acc[q][0]);
                        acc[q][1] = fmaf(a[q], b.y, acc[q][1]);
                    }
                }
            }
        }
    }
    float bv[CO_PER];
#pragma unroll
    for (int j = 0; j < CO_PER; ++j) bv[j] = bias[co0 + j];
#pragma unroll
    for (int q = 0; q < PX_PER; ++q) {
        int ox = (MODE == 1) ? (par + 2 * (px0 + q)) : (ox0 + px0 + q);
        float* op = out + (((long)n * OH + oy) * OW + ox) * COUT + co0;
        if constexpr (CO_PER == 4) {
            float4 v;
            v.x = acc[q][0] + bv[0]; v.y = acc[q][1] + bv[1];
            v.z = acc[q][2] + bv[2]; v.w = acc[q][3] + bv[3];
            if (RELU) { v.x = fmaxf(v.x, 0.f); v.y = fmaxf(v.y, 0.f);
                        v.z = fmaxf(v.z, 0.f); v.w = fmaxf(v.w, 0.f); }
            *(float4*)op = v;
        } else {
            float2 v;
            v.x = acc[q][0] + bv[0]; v.y = acc[q][1] + bv[1];
            if (RELU) { v.x = fmaxf(v.x, 0.f); v.y = fmaxf(v.y, 0.f); }
            *(float2*)op = v;
        }
    }
}

// ---------------------------------------------------------------------------
// wd2 convT 64->3 via MFMA.  h plain bf16 [16,128,128,64].
// ---------------------------------------------------------------------------
__global__ __launch_bounds__(256) void convt_final_mfma(
    const short* __restrict__ h, const short* __restrict__ Wc,
    const float* __restrict__ bias, float* __restrict__ out) {
    const int HW = 128;
    __shared__ short HB[3 * 130 * 72];
    __shared__ float Sout[6 * 260];

    const int tid = threadIdx.x;
    const int y = blockIdx.x & 127;
    const int n = blockIdx.x >> 7;
    const int lane = tid & 63, wv = tid >> 6;
    const int quad = lane >> 4, l16 = lane & 15;

    for (int u = tid; u < 780; u += TPB) {
        int row = u >> 1, half = u & 1;
        int hr = row / 130, xc = row % 130;
        int hy = y - 1 + hr, hx = xc - 1;
        bool ok = (hy >= 0 && hy < HW && hx >= 0 && hx < HW);
        const short* sp = h + ((long)(n * HW + hy) * HW + hx) * 64 + half * 32;
        uint4 a0, a1, a2, a3;
        if (ok) {
            a0 = *(const uint4*)sp;        a1 = *(const uint4*)(sp + 8);
            a2 = *(const uint4*)(sp + 16); a3 = *(const uint4*)(sp + 24);
        } else {
            a0 = make_uint4(0,0,0,0); a1 = a0; a2 = a0; a3 = a0;
        }
        short* dp = &HB[row * 72 + half * 32];
        *(uint4*)dp = a0; *(uint4*)(dp + 8) = a1;
        *(uint4*)(dp + 16) = a2; *(uint4*)(dp + 24) = a3;
    }
    __syncthreads();

#pragma unroll 1
    for (int cls = 0; cls < 4; ++cls) {
        const int py = cls >> 1, px = cls & 1;
        bf16x8 Bf[4][2];
#pragma unroll
        for (int tap = 0; tap < 4; ++tap)
#pragma unroll
            for (int cb = 0; cb < 2; ++cb)
                Bf[tap][cb] = *(const bf16x8*)&Wc[((cls * 4 + tap) * 16 + l16) * 64 + cb * 32 + quad * 8];

        f32x4 acc2[2] = { f32x4{0.f,0.f,0.f,0.f}, f32x4{0.f,0.f,0.f,0.f} };
#pragma unroll
        for (int mt = 0; mt < 2; ++mt) {
            const int xp0 = wv * 32 + mt * 16;
#pragma unroll
            for (int tap = 0; tap < 4; ++tap) {
                const int jj = tap >> 1, ii = tap & 1;
                const int hr = py - jj + 1;
                const int rbase = (hr * 130 + xp0 + l16 + px - ii + 1) * 72;
#pragma unroll
                for (int cb = 0; cb < 2; ++cb) {
                    bf16x8 Af = *(const bf16x8*)&HB[rbase + cb * 32 + quad * 8];
                    acc2[mt] = __builtin_amdgcn_mfma_f32_16x16x32_bf16(Af, Bf[tap][cb], acc2[mt], 0, 0, 0);
                }
            }
        }
        if (l16 < 3) {
#pragma unroll
            for (int mt = 0; mt < 2; ++mt)
#pragma unroll
                for (int r = 0; r < 4; ++r) {
                    int xp = wv * 32 + mt * 16 + quad * 4 + r;
                    Sout[(py * 3 + l16) * 260 + 2 * xp + px] = acc2[mt][r];
                }
        }
    }
    __syncthreads();

    for (int u = tid; u < 384; u += TPB) {
        int idx = u * 4;
        int rowi = idx >> 8;
        int xq   = idx & 255;
        int py = rowi / 3, co = rowi % 3;
        float bv = bias[co];
        float4 v = *(const float4*)&Sout[rowi * 260 + xq];
        v.x += bv; v.y += bv; v.z += bv; v.w += bv;
        *(float4*)&out[(((long)(n * 3 + co) * 256) + 2 * y + py) * 256 + xq] = v;
    }
}

// ---------------------------------------------------------------------------
// conv1: x NCHW [16,3,256,256] -> split-bf16 NHWC [16,128,128,128] + ReLU
// ---------------------------------------------------------------------------
__global__ __launch_bounds__(256) void conv1_kernel(
    const float* __restrict__ x, const float* __restrict__ Wt,
    const float* __restrict__ bias, short* __restrict__ outb) {
    const int IH = 256, IW = 256, OH = 128, OW = 128, BM = 64;
    const long APL0 = 16L * 128 * 128 * 128;
    int bx = blockIdx.x;
    int sx = bx & 1;
    int oy = (bx >> 1) & 127;
    int n  = bx >> 8;
    int ox0 = sx * BM;
    __shared__ float Bs[16 * 3 * 128];
    __shared__ float Ts[3 * 4 * 132];
    int tid = threadIdx.x;
    for (int i = tid; i < 6144 / 4; i += TPB)
        ((float4*)Bs)[i] = ((const float4*)Wt)[i];
    int iy0 = 2 * oy - 1;
    for (int idx = tid; idx < 3 * 4 * 130; idx += TPB) {
        int ci = idx / 520; int r = idx % 520;
        int ky = r / 130;   int xx = r % 130;
        int iy = iy0 + ky;  int ix = 2 * ox0 - 1 + xx;
        float v = 0.f;
        if (iy >= 0 && iy < IH && ix >= 0 && ix < IW)
            v = x[((n * 3 + ci) * IH + iy) * IW + ix];
        Ts[(ci * 4 + ky) * 132 + xx] = v;
    }
    __syncthreads();
    int cog = tid & 31, pxg = tid >> 5;
    int co0 = cog * 4, px0 = pxg * 8;
    float acc[8][4];
#pragma unroll
    for (int i = 0; i < 8; ++i)
#pragma unroll
        for (int j = 0; j < 4; ++j) acc[i][j] = 0.f;
#pragma unroll 1
    for (int ky = 0; ky < 4; ++ky)
#pragma unroll 1
        for (int kx = 0; kx < 4; ++kx)
#pragma unroll
            for (int ci = 0; ci < 3; ++ci) {
                float4 b = *(const float4*)&Bs[((ky * 4 + kx) * 3 + ci) * 128 + co0];
                const float* trow = &Ts[(ci * 4 + ky) * 132 + kx];
#pragma unroll
                for (int q = 0; q < 8; ++q) {
                    float a = trow[2 * (px0 + q)];
                    acc[q][0] = fmaf(a, b.x, acc[q][0]);
                    acc[q][1] = fmaf(a, b.y, acc[q][1]);
                    acc[q][2] = fmaf(a, b.z, acc[q][2]);
                    acc[q][3] = fmaf(a, b.w, acc[q][3]);
                }
            }
    float4 bb = *(const float4*)&bias[co0];
#pragma unroll
    for (int q = 0; q < 8; ++q) {
        int ox = ox0 + px0 + q;
        float v0 = fmaxf(acc[q][0] + bb.x, 0.f);
        float v1 = fmaxf(acc[q][1] + bb.y, 0.f);
        float v2 = fmaxf(acc[q][2] + bb.z, 0.f);
        float v3 = fmaxf(acc[q][3] + bb.w, 0.f);
        unsigned h0, l0, h1, l1;
        cvt_split2(v0, v1, h0, l0);
        cvt_split2(v2, v3, h1, l1);
        long pix = ((long)n * OH + oy) * OW + ox;
        *(uint2*)&outb[pix * 128 + co0]        = make_uint2(h0, h1);
        *(uint2*)&outb[APL0 + pix * 128 + co0] = make_uint2(l0, l1);
    }
}

// ---------------------------------------------------------------------------
__global__ void enorm_kernel(const float* __restrict__ et, const float* __restrict__ eb,
                             float* __restrict__ nt, float* __restrict__ nb) {
    int k = blockIdx.x * TPB + threadIdx.x;
    if (k >= 1024) return;
    const float* e = (k < 512) ? et : eb;
    float* o = (k < 512) ? nt : nb;
    int kk = k & 511;
    float s = 0.f;
#pragma unroll 8
    for (int d = 0; d < 64; ++d) { float v = e[d * 512 + kk]; s = fmaf(v, v, s); }
    o[kk] = s;
}

// ---------------------------------------------------------------------------
// MFMA vector quantize.  Emits fp32 qn + plain bf16 qnb; qc NCHW; one
// atomicAdd per block.
// ---------------------------------------------------------------------------
__global__ __launch_bounds__(256) void quantize_mfma(
    const float* __restrict__ f, const short* __restrict__ ET,
    const float* __restrict__ embed, const float* __restrict__ enorm,
    float* __restrict__ qn, short* __restrict__ qnb, float* __restrict__ qc,
    float* __restrict__ ido, float* __restrict__ dsum, int M, int HW) {
    __shared__ short Fh[64 * 72];
    __shared__ short Fl[64 * 72];
    __shared__ float S[64 * 65];
    __shared__ int   KI[64];
    __shared__ float wsum[4];

    const int tid = threadIdx.x;
    const int lane = tid & 63, wv = tid >> 6;
    const int quad = lane >> 4, l16 = lane & 15;
    const int R0 = blockIdx.x * 64;

    {
        int row = tid >> 2;
        int k0 = (tid & 3) * 16;
        const float* sp = f + (long)(R0 + row) * 64 + k0;
        unsigned hw[8], lw[8];
#pragma unroll
        for (int i = 0; i < 4; ++i) {
            float4 p = *(const float4*)(sp + 4 * i);
            cvt_split2(p.x, p.y, hw[2 * i], lw[2 * i]);
            cvt_split2(p.z, p.w, hw[2 * i + 1], lw[2 * i + 1]);
        }
        short* dh = &Fh[row * 72 + k0];
        short* dl = &Fl[row * 72 + k0];
        *(uint4*)(dh)     = make_uint4(hw[0], hw[1], hw[2], hw[3]);
        *(uint4*)(dh + 8) = make_uint4(hw[4], hw[5], hw[6], hw[7]);
        *(uint4*)(dl)     = make_uint4(lw[0], lw[1], lw[2], lw[3]);
        *(uint4*)(dl + 8) = make_uint4(lw[4], lw[5], lw[6], lw[7]);
    }
    __syncthreads();

    const int arow = (wv * 16 + l16) * 72;
    bf16x8 Ah0 = *(const bf16x8*)&Fh[arow + quad * 8];
    bf16x8 Ah1 = *(const bf16x8*)&Fh[arow + 32 + quad * 8];
    bf16x8 Al0 = *(const bf16x8*)&Fl[arow + quad * 8];
    bf16x8 Al1 = *(const bf16x8*)&Fl[arow + 32 + quad * 8];

    float bestv[4];
    int   besti[4];
#pragma unroll
    for (int r = 0; r < 4; ++r) { bestv[r] = 3.4e38f; besti[r] = 0; }

    const short* ETlo = ET + 32768;
#pragma unroll 2
    for (int j = 0; j < 32; ++j) {
        const int nb = (j * 16 + l16) * 64 + quad * 8;
        bf16x8 Bh0 = *(const bf16x8*)(ET + nb);
        bf16x8 Bh1 = *(const bf16x8*)(ET + nb + 32);
        bf16x8 Bl0 = *(const bf16x8*)(ETlo + nb);
        bf16x8 Bl1 = *(const bf16x8*)(ETlo + nb + 32);
        f32x4 acc = f32x4{0.f, 0.f, 0.f, 0.f};
        acc = __builtin_amdgcn_mfma_f32_16x16x32_bf16(Ah0, Bh0, acc, 0, 0, 0);
        acc = __builtin_amdgcn_mfma_f32_16x16x32_bf16(Ah1, Bh1, acc, 0, 0, 0);
        acc = __builtin_amdgcn_mfma_f32_16x16x32_bf16(Al0, Bh0, acc, 0, 0, 0);
        acc = __builtin_amdgcn_mfma_f32_16x16x32_bf16(Al1, Bh1, acc, 0, 0, 0);
        acc = __builtin_amdgcn_mfma_f32_16x16x32_bf16(Ah0, Bl0, acc, 0, 0, 0);
        acc = __builtin_amdgcn_mfma_f32_16x16x32_bf16(Ah1, Bl1, acc, 0, 0, 0);
        float en = enorm[j * 16 + l16];
        int   ni = j * 16 + l16;
#pragma unroll
        for (int r = 0; r < 4; ++r) {
            float s = fmaf(-2.f, acc[r], en);
            if (s < bestv[r]) { bestv[r] = s; besti[r] = ni; }
        }
    }
#pragma unroll
    for (int m = 1; m < 16; m <<= 1) {
#pragma unroll
        for (int r = 0; r < 4; ++r) {
            float ov = __shfl_xor(bestv[r], m);
            int   oi = __shfl_xor(besti[r], m);
            if (ov < bestv[r] || (ov == bestv[r] && oi < besti[r])) {
                bestv[r] = ov; besti[r] = oi;
            }
        }
    }
    if (l16 == 0) {
#pragma unroll
        for (int r = 0; r < 4; ++r) KI[wv * 16 + quad * 4 + r] = besti[r];
    }
    __syncthreads();

    float ddacc = 0.f;
#pragma unroll 1
    for (int r16 = 0; r16 < 16; ++r16) {
        int row = wv * 16 + r16;
        int k = KI[row];
        float ev = embed[lane * 512 + k];
        float fv = f[(long)(R0 + row) * 64 + lane];
        long qi = (long)(R0 + row) * 64 + lane;
        qn[qi] = ev;
        qnb[qi] = (short)bf16_rne(ev);
        S[row * 65 + lane] = ev;
        float dq = ev - fv;
        ddacc = fmaf(dq, dq, ddacc);
        if (lane == 0) ido[R0 + row] = (float)k;
    }
#pragma unroll
    for (int off = 1; off < 64; off <<= 1) ddacc += __shfl_xor(ddacc, off);
    if (lane == 0) wsum[wv] = ddacc;
    __syncthreads();
    if (tid == 0)
        atomicAdd(dsum, wsum[0] + wsum[1] + wsum[2] + wsum[3]);

    int nn = R0 / HW;
    int rem0 = R0 - nn * HW;
    int px = tid & 63;
    int cg = tid >> 6;
#pragma unroll
    for (int it = 0; it < 16; ++it) {
        int c = cg + 4 * it;
        qc[((long)nn * 64 + c) * HW + rem0 + px] = S[px * 65 + c];
    }
}

// ---------------------------------------------------------------------------
// ECAT concat: [DECT fp32 64ch | T1B split-bf16 reconstructed 128ch] -> fp32
// ---------------------------------------------------------------------------
__global__ void concat_rec_kernel(const float* __restrict__ a, const short* __restrict__ bh,
                                  float* __restrict__ o, int M) {
    const long PLB = 8388608L;   // 16*64*64*128
    int idx = blockIdx.x * TPB + threadIdx.x;
    if (idx >= M * 48) return;
    int row = idx / 48;
    int c4  = (idx - row * 48) * 4;
    float4 v;
    if (c4 < 64) v = *(const float4*)(a + (long)row * 64 + c4);
    else {
        int cc = c4 - 64;
        uint2 h = *(const uint2*)(bh + (long)row * 128 + cc);
        uint2 l = *(const uint2*)(bh + PLB + (long)row * 128 + cc);
        v.x = __uint_as_float(h.x << 16)         + __uint_as_float(l.x << 16);
        v.y = __uint_as_float(h.x & 0xFFFF0000u) + __uint_as_float(l.x & 0xFFFF0000u);
        v.z = __uint_as_float(h.y << 16)         + __uint_as_float(l.y << 16);
        v.w = __uint_as_float(h.y & 0xFFFF0000u) + __uint_as_float(l.y & 0xFFFF0000u);
    }
    *(float4*)(o + (long)row * 192 + c4) = v;
}

// ---------------------------------------------------------------------------
// QCAT concat (plain bf16): ch0-63 = cvt(UPT fp32), ch64-127 = QBNB copy.
// ---------------------------------------------------------------------------
__global__ void concat_qcat_kernel(const float* __restrict__ a, const short* __restrict__ qh,
                                   short* __restrict__ o, int M) {
    int idx = blockIdx.x * TPB + threadIdx.x;
    if (idx >= M * 32) return;
    int row = idx / 32;
    int c4  = (idx - row * 32) * 4;
    uint2 w;
    if (c4 < 64) {
        float4 v = *(const float4*)(a + (long)row * 64 + c4);
        w = make_uint2(cvt_pk(v.x, v.y), cvt_pk(v.z, v.w));
    } else {
        w = *(const uint2*)(qh + (long)row * 64 + (c4 - 64));
    }
    *(uint2*)(o + (long)row * 128 + c4) = w;
}

// ---------------------------------------------------------------------------
__global__ void loss_kernel(const float* __restrict__ sums, float* __restrict__ out) {
    out[0] = sums[0] * (1.f / (16384.f * 64.f)) + sums[1] * (1.f / (65536.f * 64.f));
}

// ---------------------------------------------------------------------------
extern "C" void kernel_launch(void* const* d_in, const int* in_sizes, int n_in,
                              void* d_out, int out_size, void* d_ws, size_t ws_size,
                              hipStream_t stream) {
    const float* x   = (const float*)d_in[0];
    const float* wb1 = (const float*)d_in[1];  const float* bb1 = (const float*)d_in[2];
    const float* wb2 = (const float*)d_in[3];  const float* bb2 = (const float*)d_in[4];
    const float* wt1 = (const float*)d_in[5];  const float* bt1 = (const float*)d_in[6];
    const float* wqt = (const float*)d_in[7];  const float* bqt = (const float*)d_in[8];
    const float* embed_t = (const float*)d_in[9];
    const float* wdt = (const float*)d_in[10]; const float* bdt = (const float*)d_in[11];
    const float* wqb = (const float*)d_in[12]; const float* bqb = (const float*)d_in[13];
    const float* embed_b = (const float*)d_in[14];
    const float* wup = (const float*)d_in[15]; const float* bup = (const float*)d_in[16];
    const float* wd1 = (const float*)d_in[17]; const float* bd1 = (const float*)d_in[18];
    const float* wd2 = (const float*)d_in[19]; const float* bd2 = (const float*)d_in[20];
    float* out = (float*)d_out;
    float* ws  = (float*)d_ws;

    float* O_XHAT = out;
    float* O_QT   = out + 3145728;
    float* O_QB   = out + 4194304;
    float* O_LOSS = out + 8388608;
    float* O_IDT  = out + 8388609;
    float* O_IDB  = out + 8404993;

    // ws layout (float-slot offsets)
    float* W_WB1  = ws + 0;                    // 6144 fp32 (conv1)
    short* WB_WD2 = (short*)(ws + 16384);      // 16384 sh
    short* ET_T   = (short*)(ws + 32768);      // 65536 sh
    short* ET_B   = (short*)(ws + 65536);      // 65536 sh
    short* WB_WQT = (short*)(ws + 98304);      // 16384 sh (split 1x1 128->64)
    float* W_WDT  = ws + 540672;               // 65536 fp32 (exact convT 64->64)
    float* W_WQB  = ws + 606208;               // 12288 fp32 (exact 1x1 192->64)
    float* EN_T  = ws + 818176;
    float* EN_B  = ws + 818688;
    float* SUMS  = ws + 819200;
    short* T1B   = (short*)(ws + 1048576);     // split [2][16,64,64,128]
    const long BIG = 9437184;
    short* T0B   = (short*)(ws + BIG);         // split [2][16,128,128,128]
    short* T2B   = (short*)(ws + BIG);         // split [2][16,32,32,128] (T0B dead)
    float* QT    = ws + BIG + 2097152;         // fp32 [16384,64]
    float* QTN   = ws + BIG + 3145728;         // fp32 quant_t rows (for wdt)
    short* QTNB  = (short*)(ws + BIG + 4194304);  // plain bf16 (for wup)
    float* DECT  = ws + BIG + 4718592;         // fp32 [16,64,64,64]
    float* ECAT  = ws + BIG + 8912896;         // fp32 [16,64,64,192]
    float* QB    = ws + BIG + 21495808;        // fp32 [65536,64]
    short* QBNB  = (short*)(ws + BIG + 25690112); // plain bf16 [65536,64]
    float* QND   = ws + BIG + 27787264;        // fp32 dump (bottom qn, unused)
    float* UPT   = ws + BIG + 4718592;         // fp32, reuses DECT
    short* QCATB = (short*)(ws + BIG + 8912896);  // plain bf16, reuses ECAT
    short* HBUFB = (short*)(ws + BIG + 16777216); // plain bf16 [16,128,128,64]
    short* WB_BF2 = (short*)(ws + 42991616);
    short* WB_BT1 = (short*)(ws + 43253760);
    short* WB_BD1 = (short*)(ws + 43515904);
    short* WB_BUP = (short*)(ws + 43646976);

    auto wt_launch = [&](const float* src, float* dst, int cin, int cout, int taps, int iohw) {
        int tot = cin * cout * taps;
        wtrans_kernel<<<(tot + TPB - 1) / TPB, TPB, 0, stream>>>(src, dst, cin, cout, taps, iohw);
    };
    auto wtb_launch = [&](const float* src, short* dst, int cin, int cout, int taps, int iohw) {
        int tot = cin * cout * taps;
        wtrans_bf16_kernel<<<(tot + TPB - 1) / TPB, TPB, 0, stream>>>(src, dst, cin, cout, taps, iohw, tot);
    };
    wt_launch(wb1, W_WB1, 3, 128, 16, 0);
    wt_launch(wdt, W_WDT, 64, 64, 16, 1);
    wt_launch(wqb, W_WQB, 192, 64, 1, 0);
    wtrans_wd2_kernel<<<64, TPB, 0, stream>>>(wd2, WB_WD2);
    wtb_launch(wb2, WB_BF2, 128, 128, 16, 0);
    wtb_launch(wt1, WB_BT1, 128, 128, 16, 0);
    wtb_launch(wqt, WB_WQT, 128, 64, 1, 0);
    wtb_launch(wd1, WB_BD1, 128, 64, 16, 1);
    wtb_launch(wup, WB_BUP, 64, 64, 16, 1);
    enorm_kernel<<<4, TPB, 0, stream>>>(embed_t, embed_b, EN_T, EN_B);
    etrans_kernel<<<256, TPB, 0, stream>>>(embed_t, embed_b, ET_T, ET_B);
    hipError_t e0 = hipMemsetAsync((void*)SUMS, 0, 2 * sizeof(float), stream);
    (void)e0;

    // ----- encode -----
    conv1_kernel<<<4096, TPB, 0, stream>>>(x, W_WB1, bb1, T0B);
    // conv2: split in/out, KR=32, NSP=2 (grid 1024 = 4 blk/CU, LDS ~31KB)
    mfma_conv<0, 128, 128, 1, 1, 128, 128, 64, 64, 2, 1, 3, 32, 2>
        <<<1024, TPB, 0, stream>>>(T0B, WB_BF2, bb2, nullptr, T1B);
    // conv3: split in/out, NSP=2 (grid 256 — was 128 = half-GPU idle)
    mfma_conv<0, 128, 128, 1, 1, 64, 64, 32, 32, 4, 1, 3, 32, 2>
        <<<256, TPB, 0, stream>>>(T1B, WB_BT1, bt1, nullptr, T2B);
    // wqt 1x1: split MFMA, fp32 out
    mfma_conv<2, 128, 64, 1, 0, 32, 32, 32, 32, 4, 1, 0, 64, 1>
        <<<128, TPB, 0, stream>>>(T2B, WB_WQT, bqt, QT, nullptr);
    quantize_mfma<<<256, TPB, 0, stream>>>(QT, ET_T, embed_t, EN_T, QTN, QTNB,
                                           O_QT, O_IDT, SUMS, 16384, 1024);
    // wdt: fp32 exact (id_b-critical)
    conv_gemm<1, 64, 64, 32, 0, 32, 32, 64, 64><<<2048, TPB, 0, stream>>>(QTN, W_WDT, bdt, DECT);
    concat_rec_kernel<<<12288, TPB, 0, stream>>>(DECT, T1B, ECAT, 65536);
    // wqb: fp32 exact (id_b-critical)
    conv_gemm<2, 192, 64, 64, 0, 64, 64, 64, 64><<<1024, TPB, 0, stream>>>(ECAT, W_WQB, bqb, QB);
    quantize_mfma<<<1024, TPB, 0, stream>>>(QB, ET_B, embed_b, EN_B, QND, QBNB,
                                            O_QB, O_IDB, SUMS + 1, 65536, 4096);
    // ----- decode -----
    // wup: plain bf16 in (QTNB), KR=64, fp32 out
    mfma_conv<1, 64, 64, 0, 0, 32, 32, 64, 64, 4, 1, 0, 64, 1>
        <<<512, TPB, 0, stream>>>(QTNB, WB_BUP, bup, UPT, nullptr);
    concat_qcat_kernel<<<8192, TPB, 0, stream>>>(UPT, QBNB, QCATB, 65536);
    // dec1: plain bf16 in, KR=64, plain bf16 out + ReLU
    mfma_conv<1, 128, 64, 0, 1, 64, 64, 128, 128, 2, 1, 2, 64, 1>
        <<<2048, TPB, 0, stream>>>(QCATB, WB_BD1, bd1, nullptr, HBUFB);
    convt_final_mfma<<<2048, TPB, 0, stream>>>(HBUFB, WB_WD2, bd2, O_XHAT);
    loss_kernel<<<1, 1, 0, stream>>>(SUMS, O_LOSS);

    (void)in_sizes; (void)n_in; (void)out_size; (void)ws_size;
}

// Round 11
// 718.783 us; speedup vs baseline: 1.1371x; 1.1371x over previous
//
#include <hip/hip_runtime.h>

#define TPB 256

typedef __attribute__((ext_vector_type(4))) float f32x4;
typedef __attribute__((ext_vector_type(8))) short bf16x8;

// ---------------------------------------------------------------------------
// Weight transform fp32: src OIHW (iohw=0) or IOHW (iohw=1) -> [tap][ci][co]
// ---------------------------------------------------------------------------
__global__ void wtrans_kernel(const float* __restrict__ src, float* __restrict__ dst,
                              int CIN, int COUT, int taps, int iohw) {
    int idx = blockIdx.x * TPB + threadIdx.x;
    int tot = CIN * COUT * taps;
    if (idx >= tot) return;
    int co = idx % COUT;
    int ci = (idx / COUT) % CIN;
    int tap = idx / (COUT * CIN);
    float v = iohw ? src[(ci * COUT + co) * taps + tap]
                   : src[(co * CIN + ci) * taps + tap];
    dst[idx] = v;
}

// ---------------------------------------------------------------------------
__device__ __forceinline__ unsigned bf16_rne(float v) {
    unsigned u = __float_as_uint(v);
    return (u + 0x7FFFu + ((u >> 16) & 1u)) >> 16;
}

// ---------------------------------------------------------------------------
// Weight transform bf16-split: fp32 -> hi plane [tap][co][ci], lo at +PL.
// ---------------------------------------------------------------------------
__global__ void wtrans_bf16_kernel(const float* __restrict__ src, short* __restrict__ dst,
                                   int CIN, int COUT, int taps, int iohw, int PL) {
    int idx = blockIdx.x * TPB + threadIdx.x;
    int tot = CIN * COUT * taps;
    if (idx >= tot) return;
    int ci = idx % CIN;
    int co = (idx / CIN) % COUT;
    int tap = idx / (CIN * COUT);
    float v = iohw ? src[(ci * COUT + co) * taps + tap]
                   : src[(co * CIN + ci) * taps + tap];
    unsigned h = bf16_rne(v);
    float rem = v - __uint_as_float(h << 16);
    dst[idx] = (short)h;
    dst[idx + PL] = (short)bf16_rne(rem);
}

// ---------------------------------------------------------------------------
// wd2 weights -> bf16 [cls(4)][tap(4)][co(16 pad from 3)][ci(64)]
// ---------------------------------------------------------------------------
__global__ void wtrans_wd2_kernel(const float* __restrict__ src, short* __restrict__ dst) {
    int idx = blockIdx.x * TPB + threadIdx.x;
    if (idx >= 16384) return;
    int ci  = idx & 63;
    int co  = (idx >> 6) & 15;
    int tap = (idx >> 10) & 3;
    int cls = idx >> 12;
    int py = cls >> 1, px = cls & 1;
    int jj = tap >> 1, ii = tap & 1;
    int ky = (1 - py) + 2 * jj;
    int kx = (1 - px) + 2 * ii;
    float v = (co < 3) ? src[(ci * 3 + co) * 16 + ky * 4 + kx] : 0.f;
    dst[idx] = (short)bf16_rne(v);
}

// ---------------------------------------------------------------------------
// embed [64,512] fp32 -> transposed split bf16 [n=512][k=64], hi | lo planes.
// ---------------------------------------------------------------------------
__global__ void etrans_kernel(const float* __restrict__ et, const float* __restrict__ eb,
                              short* __restrict__ ETt, short* __restrict__ ETb) {
    int idx = blockIdx.x * TPB + threadIdx.x;
    if (idx >= 65536) return;
    const float* src = (idx < 32768) ? et : eb;
    short* dst = (idx < 32768) ? ETt : ETb;
    int i = idx & 32767;
    int k = i & 63;
    int n = i >> 6;
    float v = src[k * 512 + n];
    unsigned h = bf16_rne(v);
    float rem = v - __uint_as_float(h << 16);
    dst[i] = (short)h;
    dst[i + 32768] = (short)bf16_rne(rem);
}

// ---------------------------------------------------------------------------
__device__ __forceinline__ void cvt_split2(float a, float b, unsigned& hw, unsigned& lw) {
    unsigned ha = bf16_rne(a), hb = bf16_rne(b);
    float ra = a - __uint_as_float(ha << 16);
    float rb = b - __uint_as_float(hb << 16);
    hw = ha | (hb << 16);
    lw = bf16_rne(ra) | (bf16_rne(rb) << 16);
}
__device__ __forceinline__ unsigned cvt_pk(float a, float b) {
    return bf16_rne(a) | (bf16_rne(b) << 16);
}

// ---------------------------------------------------------------------------
// Swizzled LDS index: 16B group g (8 shorts) of row stored at g^((row>>3)&3)
// within its 32-short chunk.  Breaks the period-8 bank collision of strided
// row bases while keeping 16B alignment for b128 ops.
// ---------------------------------------------------------------------------
template<int ST>
__device__ __forceinline__ int lidx(int row, int koff) {
    int g  = (koff >> 3) & 3;
    int kc = koff & ~31;
    int gs = g ^ ((row >> 3) & 3);
    return row * ST + kc + (gs << 3);
}

// ---------------------------------------------------------------------------
// MFMA implicit-GEMM conv.  bf16(-split) compute; staging is uint4 copy when
// INBF=1.  MODE 0: 4x4 s2 p1 conv.  MODE 1: convT (4 parity classes).
// MODE 2: 1x1.  OUTB: 0 = fp32; 2 = plain bf16; 3 = split bf16.
// KR: K per barrier round.  NSP: co-split factor.  For NSP=2 the co-half is
// taken from bit 3 of blockIdx so the two halves of one spatial tile land on
// the SAME XCD (bx%8 round-robin) adjacent in XCD-local order -> the second
// member's A-reads hit that XCD's L2 instead of refetching from HBM.
// Grid must be divisible by 16 when NSP=2.
// ---------------------------------------------------------------------------
template<int MODE, int CIN, int COUT, int SPLIT, int RELU,
         int IH, int IW, int OH, int OW, int R, int INBF, int OUTB, int KR, int NSP>
__global__ __launch_bounds__(256) void mfma_conv(
    const void* __restrict__ inv, const short* __restrict__ Wb,
    const float* __restrict__ bias, float* __restrict__ outp,
    short* __restrict__ outb) {
    constexpr int TAPS = (MODE == 0) ? 16 : (MODE == 1 ? 4 : 1);
    constexpr int CW = (MODE == 1) ? OW / 2 : OW;
    constexpr int CH = (MODE == 1) ? OH / 2 : OH;
    constexpr int NCOUT = COUT / NSP;           // logical cout per block
    constexpr int NRND = CIN / KR;
    constexpr int KC = KR / 32;
    constexpr int ST = KR + 8;
    constexpr int MTc = (NCOUT == 128) ? 4 : 2;
    constexpr long PLW = (long)TAPS * COUT * CIN;
    constexpr long APL_IN  = 16L * IH * IW * CIN;
    constexpr long APL_OUT = 16L * OH * OW * COUT;
    constexpr int NU4A = KR / 16;
    constexpr int TPR  = 256 / NCOUT;
    constexpr int SPT  = KR / TPR;
    constexpr int NU4B = SPT / 8;

    __shared__ short Ah[128 * ST];
    __shared__ short Al[SPLIT ? 128 * ST : 8];
    __shared__ short Bh[NCOUT * ST];
    __shared__ short Bl[SPLIT ? NCOUT * ST : 8];

    int bx = blockIdx.x;
    int co_off = 0;
    if (NSP == 2) {
        // co-half from bit 3: pairs (bx, bx+8) share spatial tile AND XCD.
        co_off = ((bx >> 3) & 1) * NCOUT;
        bx = (bx & 7) | ((bx >> 4) << 3);
    }
    int ry = 0, rx = 0;
    if (MODE == 1) { int c = bx & 3; ry = c >> 1; rx = c & 1; bx >>= 2; }
    const int y0 = (bx % (CH / R)) * R;
    const int n  = bx / (CH / R);

    const int tid = threadIdx.x;
    const int p   = tid >> 1;
    const int akb = (tid & 1) * (KR / 2);
    const int rr = p / CW, xx = p % CW;
    const int bco = tid / TPR;
    const int bk  = (tid % TPR) * SPT;
    const int lane = tid & 63, wv = tid >> 6;
    const int quad = lane >> 4, l16 = lane & 15;
    const int mbase = (NCOUT == 128) ? (wv & 1) * 64 : wv * 32;
    const int nbase = (NCOUT == 128) ? (wv >> 1) * 64 : 0;

    f32x4 acc[MTc][4];
#pragma unroll
    for (int mt = 0; mt < MTc; ++mt)
#pragma unroll
        for (int nt = 0; nt < 4; ++nt) acc[mt][nt] = f32x4{0.f, 0.f, 0.f, 0.f};

#pragma unroll 1
    for (int tap = 0; tap < TAPS; ++tap) {
        int iy, ix, wt;
        if (MODE == 0) {
            int ky = tap >> 2, kx = tap & 3;
            iy = 2 * (y0 + rr) - 1 + ky;
            ix = 2 * xx - 1 + kx;
            wt = tap;
        } else if (MODE == 1) {
            int jj = tap >> 1, ii = tap & 1;
            iy = (y0 + rr) + ry - jj;
            ix = xx + rx - ii;
            wt = ((1 - ry) + 2 * jj) * 4 + ((1 - rx) + 2 * ii);
        } else {
            iy = y0 + rr; ix = xx; wt = 0;
        }
        const bool av = (MODE == 2) ||
                        ((iy >= 0) && (iy < IH) && (ix >= 0) && (ix < IW));
        const long abase = ((long)(n * IH + iy) * IW + ix) * CIN + akb;

#pragma unroll 1
        for (int ko = 0; ko < NRND; ++ko) {
            __syncthreads();
            if constexpr (INBF) {
                const short* sb = (const short*)inv + abase + ko * KR;
#pragma unroll
                for (int u = 0; u < NU4A; ++u) {
                    uint4 h = av ? *(const uint4*)(sb + 8 * u) : make_uint4(0, 0, 0, 0);
                    *(uint4*)&Ah[lidx<ST>(p, akb + 8 * u)] = h;
                }
                if constexpr (SPLIT) {
#pragma unroll
                    for (int u = 0; u < NU4A; ++u) {
                        uint4 l = av ? *(const uint4*)(sb + APL_IN + 8 * u) : make_uint4(0, 0, 0, 0);
                        *(uint4*)&Al[lidx<ST>(p, akb + 8 * u)] = l;
                    }
                }
            } else {
                const float* sp = (const float*)inv + abase + ko * KR;
#pragma unroll
                for (int u = 0; u < NU4A; ++u) {
                    float4 f0, f1;
                    if (av) { f0 = *(const float4*)(sp + 8 * u); f1 = *(const float4*)(sp + 8 * u + 4); }
                    else { f0.x=f0.y=f0.z=f0.w=0.f; f1 = f0; }
                    unsigned h0, l0, h1, l1, h2, l2, h3, l3;
                    cvt_split2(f0.x, f0.y, h0, l0); cvt_split2(f0.z, f0.w, h1, l1);
                    cvt_split2(f1.x, f1.y, h2, l2); cvt_split2(f1.z, f1.w, h3, l3);
                    *(uint4*)&Ah[lidx<ST>(p, akb + 8 * u)] = make_uint4(h0, h1, h2, h3);
                    if constexpr (SPLIT)
                        *(uint4*)&Al[lidx<ST>(p, akb + 8 * u)] = make_uint4(l0, l1, l2, l3);
                }
            }
            {
                const short* wr = Wb + ((long)wt * COUT + co_off + bco) * CIN + ko * KR + bk;
#pragma unroll
                for (int u = 0; u < NU4B; ++u) {
                    *(uint4*)&Bh[lidx<ST>(bco, bk + 8 * u)] = *(const uint4*)(wr + 8 * u);
                    if constexpr (SPLIT)
                        *(uint4*)&Bl[lidx<ST>(bco, bk + 8 * u)] = *(const uint4*)(wr + PLW + 8 * u);
                }
            }
            __syncthreads();
#pragma unroll
            for (int kc = 0; kc < KC; ++kc) {
                bf16x8 ahf[MTc], alf[SPLIT ? MTc : 1];
#pragma unroll
                for (int mt = 0; mt < MTc; ++mt) {
                    int mrow = mbase + mt * 16 + l16;
                    ahf[mt] = *(const bf16x8*)&Ah[lidx<ST>(mrow, kc * 32 + quad * 8)];
                    if constexpr (SPLIT)
                        alf[mt] = *(const bf16x8*)&Al[lidx<ST>(mrow, kc * 32 + quad * 8)];
                }
#pragma unroll
                for (int nt = 0; nt < 4; ++nt) {
                    int nrow = nbase + nt * 16 + l16;
                    bf16x8 bhf = *(const bf16x8*)&Bh[lidx<ST>(nrow, kc * 32 + quad * 8)];
#pragma unroll
                    for (int mt = 0; mt < MTc; ++mt)
                        acc[mt][nt] = __builtin_amdgcn_mfma_f32_16x16x32_bf16(ahf[mt], bhf, acc[mt][nt], 0, 0, 0);
                    if constexpr (SPLIT) {
                        bf16x8 blf = *(const bf16x8*)&Bl[lidx<ST>(nrow, kc * 32 + quad * 8)];
#pragma unroll
                        for (int mt = 0; mt < MTc; ++mt) {
                            acc[mt][nt] = __builtin_amdgcn_mfma_f32_16x16x32_bf16(alf[mt], bhf, acc[mt][nt], 0, 0, 0);
                            acc[mt][nt] = __builtin_amdgcn_mfma_f32_16x16x32_bf16(ahf[mt], blf, acc[mt][nt], 0, 0, 0);
                        }
                    }
                }
            }
        }
    }
#pragma unroll
    for (int mt = 0; mt < MTc; ++mt)
#pragma unroll
        for (int nt = 0; nt < 4; ++nt) {
            int co = co_off + nbase + nt * 16 + l16;
            float bv = bias[co];
#pragma unroll
            for (int r = 0; r < 4; ++r) {
                int pl = mbase + mt * 16 + quad * 4 + r;
                int rr2 = pl / CW, x2 = pl % CW;
                int oy, ox;
                if (MODE == 1) { oy = 2 * (y0 + rr2) + ry; ox = 2 * x2 + rx; }
                else           { oy = y0 + rr2; ox = x2; }
                float vv = acc[mt][nt][r] + bv;
                if (RELU) vv = fmaxf(vv, 0.f);
                long oidx = ((long)(n * OH + oy) * OW + ox) * COUT + co;
                if constexpr (OUTB == 0) outp[oidx] = vv;
                if constexpr (OUTB == 3) {
                    unsigned hh = bf16_rne(vv);
                    outb[oidx] = (short)hh;
                    outb[oidx + APL_OUT] = (short)bf16_rne(vv - __uint_as_float(hh << 16));
                }
                if constexpr (OUTB == 2) outb[oidx] = (short)bf16_rne(vv);
            }
        }
}

// ---------------------------------------------------------------------------
// Generic fp32 tiled conv-as-GEMM (wdt / wqb — id-critical exact path).
// ---------------------------------------------------------------------------
template<int MODE, int CIN, int COUT, int BM, int RELU, int IH, int IW, int OH, int OW>
__global__ __launch_bounds__(256) void conv_gemm(
    const float* __restrict__ in, const float* __restrict__ Wt,
    const float* __restrict__ bias, float* __restrict__ out) {
    constexpr int CHUNK  = 64;
    constexpr int NCH    = CIN / CHUNK;
    constexpr int CO_PER = (COUT == 128) ? 4 : 2;
    constexpr int PX_PER = BM / 8;
    constexpr int TAPS   = (MODE == 0) ? 16 : (MODE == 1 ? 4 : 1);
    __shared__ float As[CHUNK * BM];
    __shared__ float Bs[CHUNK * COUT];
    const int tid = threadIdx.x;
    const int bx  = blockIdx.x;
    int n, oy, ox0 = 0, par = 0;
    if (MODE == 1) {
        par = bx & 1;
        oy  = (bx >> 1) % OH;
        n   = bx / (2 * OH);
    } else {
        constexpr int SPR = OW / BM;
        int s = bx % SPR;
        oy = (bx / SPR) % OH;
        n  = bx / (SPR * OH);
        ox0 = s * BM;
    }
    const int cog = tid & 31;
    const int pxg = tid >> 5;
    const int co0 = cog * CO_PER, px0 = pxg * PX_PER;
    float acc[PX_PER][CO_PER];
#pragma unroll
    for (int q = 0; q < PX_PER; ++q)
#pragma unroll
        for (int j = 0; j < CO_PER; ++j) acc[q][j] = 0.f;
    constexpr int TPX  = 256 / BM;
    constexpr int CIPT = CHUNK / TPX;
    const int spx  = tid / TPX;
    const int sci0 = (tid % TPX) * CIPT;
    const int py   = oy & 1;

#pragma unroll 1
    for (int tap = 0; tap < TAPS; ++tap) {
        int iy, twi, sx;
        if (MODE == 0) {
            int ky = tap >> 2, kx = tap & 3;
            iy  = 2 * oy - 1 + ky;
            sx  = 2 * (ox0 + spx) - 1 + kx;
            twi = tap;
        } else if (MODE == 1) {
            int jj = tap >> 1, ii = tap & 1;
            iy  = ((oy + 1) >> 1) - jj;
            sx  = spx + par - ii;
            twi = ((1 - py) + 2 * jj) * 4 + ((1 - par) + 2 * ii);
        } else {
            iy = oy; sx = ox0 + spx; twi = 0;
        }
        const bool pxv = (iy >= 0) && (iy < IH) && (sx >= 0) && (sx < IW);
        const float* srcp = in + (((long)n * IH + iy) * IW + sx) * CIN + sci0;
#pragma unroll 1
        for (int cb = 0; cb < NCH; ++cb) {
            __syncthreads();
            float4 tmp[CIPT / 4];
#pragma unroll
            for (int t4 = 0; t4 < CIPT / 4; ++t4) {
                if (pxv) tmp[t4] = *(const float4*)(srcp + cb * CHUNK + 4 * t4);
                else { tmp[t4].x = 0.f; tmp[t4].y = 0.f; tmp[t4].z = 0.f; tmp[t4].w = 0.f; }
            }
#pragma unroll
            for (int t4 = 0; t4 < CIPT / 4; ++t4) {
                As[(sci0 + 4 * t4 + 0) * BM + spx] = tmp[t4].x;
                As[(sci0 + 4 * t4 + 1) * BM + spx] = tmp[t4].y;
                As[(sci0 + 4 * t4 + 2) * BM + spx] = tmp[t4].z;
                As[(sci0 + 4 * t4 + 3) * BM + spx] = tmp[t4].w;
            }
            {
                const float4* wsrc = (const float4*)(Wt + ((long)twi * CIN + cb * CHUNK) * COUT);
#pragma unroll
                for (int t4 = 0; t4 < (CHUNK * COUT) / 1024; ++t4)
                    ((float4*)Bs)[tid + 256 * t4] = wsrc[tid + 256 * t4];
            }
            __syncthreads();
#pragma unroll 4
            for (int k = 0; k < CHUNK; ++k) {
                float a[PX_PER];
#pragma unroll
                for (int t4 = 0; t4 < PX_PER / 4; ++t4)
                    *(float4*)&a[4 * t4] = *(const float4*)&As[k * BM + px0 + 4 * t4];
                if constexpr (CO_PER == 4) {
                    float4 b = *(const float4*)&Bs[k * COUT + co0];
#pragma unroll
                    for (int q = 0; q < PX_PER; ++q) {
                        acc[q][0] = fmaf(a[q], b.x, acc[q][0]);
                        acc[q][1] = fmaf(a[q], b.y, acc[q][1]);
                        acc[q][2] = fmaf(a[q], b.z, acc[q][2]);
                        acc[q][3] = fmaf(a[q], b.w, acc[q][3]);
                    }
                } else {
                    float2 b = *(const float2*)&Bs[k * COUT + co0];
#pragma unroll
                    for (int q = 0; q < PX_PER; ++q) {
                        acc[q][0] = fmaf(a[q], b.x, acc[q][0]);
                        acc[q][1] = fmaf(a[q], b.y, acc[q][1]);
                    }
                }
            }
        }
    }
    float bv[CO_PER];
#pragma unroll
    for (int j = 0; j < CO_PER; ++j) bv[j] = bias[co0 + j];
#pragma unroll
    for (int q = 0; q < PX_PER; ++q) {
        int ox = (MODE == 1) ? (par + 2 * (px0 + q)) : (ox0 + px0 + q);
        float* op = out + (((long)n * OH + oy) * OW + ox) * COUT + co0;
        if constexpr (CO_PER == 4) {
            float4 v;
            v.x = acc[q][0] + bv[0]; v.y = acc[q][1] + bv[1];
            v.z = acc[q][2] + bv[2]; v.w = acc[q][3] + bv[3];
            if (RELU) { v.x = fmaxf(v.x, 0.f); v.y = fmaxf(v.y, 0.f);
                        v.z = fmaxf(v.z, 0.f); v.w = fmaxf(v.w, 0.f); }
            *(float4*)op = v;
        } else {
            float2 v;
            v.x = acc[q][0] + bv[0]; v.y = acc[q][1] + bv[1];
            if (RELU) { v.x = fmaxf(v.x, 0.f); v.y = fmaxf(v.y, 0.f); }
            *(float2*)op = v;
        }
    }
}

// ---------------------------------------------------------------------------
// wd2 convT 64->3 via MFMA.  h plain bf16 [16,128,128,64].
// ---------------------------------------------------------------------------
__global__ __launch_bounds__(256) void convt_final_mfma(
    const short* __restrict__ h, const short* __restrict__ Wc,
    const float* __restrict__ bias, float* __restrict__ out) {
    const int HW = 128;
    __shared__ short HB[3 * 130 * 72];
    __shared__ float Sout[6 * 260];

    const int tid = threadIdx.x;
    const int y = blockIdx.x & 127;
    const int n = blockIdx.x >> 7;
    const int lane = tid & 63, wv = tid >> 6;
    const int quad = lane >> 4, l16 = lane & 15;

    for (int u = tid; u < 780; u += TPB) {
        int row = u >> 1, half = u & 1;
        int hr = row / 130, xc = row % 130;
        int hy = y - 1 + hr, hx = xc - 1;
        bool ok = (hy >= 0 && hy < HW && hx >= 0 && hx < HW);
        const short* sp = h + ((long)(n * HW + hy) * HW + hx) * 64 + half * 32;
        uint4 a0, a1, a2, a3;
        if (ok) {
            a0 = *(const uint4*)sp;        a1 = *(const uint4*)(sp + 8);
            a2 = *(const uint4*)(sp + 16); a3 = *(const uint4*)(sp + 24);
        } else {
            a0 = make_uint4(0,0,0,0); a1 = a0; a2 = a0; a3 = a0;
        }
        short* dp = &HB[row * 72 + half * 32];
        *(uint4*)dp = a0; *(uint4*)(dp + 8) = a1;
        *(uint4*)(dp + 16) = a2; *(uint4*)(dp + 24) = a3;
    }
    __syncthreads();

#pragma unroll 1
    for (int cls = 0; cls < 4; ++cls) {
        const int py = cls >> 1, px = cls & 1;
        bf16x8 Bf[4][2];
#pragma unroll
        for (int tap = 0; tap < 4; ++tap)
#pragma unroll
            for (int cb = 0; cb < 2; ++cb)
                Bf[tap][cb] = *(const bf16x8*)&Wc[((cls * 4 + tap) * 16 + l16) * 64 + cb * 32 + quad * 8];

        f32x4 acc2[2] = { f32x4{0.f,0.f,0.f,0.f}, f32x4{0.f,0.f,0.f,0.f} };
#pragma unroll
        for (int mt = 0; mt < 2; ++mt) {
            const int xp0 = wv * 32 + mt * 16;
#pragma unroll
            for (int tap = 0; tap < 4; ++tap) {
                const int jj = tap >> 1, ii = tap & 1;
                const int hr = py - jj + 1;
                const int rbase = (hr * 130 + xp0 + l16 + px - ii + 1) * 72;
#pragma unroll
                for (int cb = 0; cb < 2; ++cb) {
                    bf16x8 Af = *(const bf16x8*)&HB[rbase + cb * 32 + quad * 8];
                    acc2[mt] = __builtin_amdgcn_mfma_f32_16x16x32_bf16(Af, Bf[tap][cb], acc2[mt], 0, 0, 0);
                }
            }
        }
        if (l16 < 3) {
#pragma unroll
            for (int mt = 0; mt < 2; ++mt)
#pragma unroll
                for (int r = 0; r < 4; ++r) {
                    int xp = wv * 32 + mt * 16 + quad * 4 + r;
                    Sout[(py * 3 + l16) * 260 + 2 * xp + px] = acc2[mt][r];
                }
        }
    }
    __syncthreads();

    for (int u = tid; u < 384; u += TPB) {
        int idx = u * 4;
        int rowi = idx >> 8;
        int xq   = idx & 255;
        int py = rowi / 3, co = rowi % 3;
        float bv = bias[co];
        float4 v = *(const float4*)&Sout[rowi * 260 + xq];
        v.x += bv; v.y += bv; v.z += bv; v.w += bv;
        *(float4*)&out[(((long)(n * 3 + co) * 256) + 2 * y + py) * 256 + xq] = v;
    }
}

// ---------------------------------------------------------------------------
// conv1: x NCHW [16,3,256,256] -> split-bf16 NHWC [16,128,128,128] + ReLU
// ---------------------------------------------------------------------------
__global__ __launch_bounds__(256) void conv1_kernel(
    const float* __restrict__ x, const float* __restrict__ Wt,
    const float* __restrict__ bias, short* __restrict__ outb) {
    const int IH = 256, IW = 256, OH = 128, OW = 128, BM = 64;
    const long APL0 = 16L * 128 * 128 * 128;
    int bx = blockIdx.x;
    int sx = bx & 1;
    int oy = (bx >> 1) & 127;
    int n  = bx >> 8;
    int ox0 = sx * BM;
    __shared__ float Bs[16 * 3 * 128];
    __shared__ float Ts[3 * 4 * 132];
    int tid = threadIdx.x;
    for (int i = tid; i < 6144 / 4; i += TPB)
        ((float4*)Bs)[i] = ((const float4*)Wt)[i];
    int iy0 = 2 * oy - 1;
    for (int idx = tid; idx < 3 * 4 * 130; idx += TPB) {
        int ci = idx / 520; int r = idx % 520;
        int ky = r / 130;   int xx = r % 130;
        int iy = iy0 + ky;  int ix = 2 * ox0 - 1 + xx;
        float v = 0.f;
        if (iy >= 0 && iy < IH && ix >= 0 && ix < IW)
            v = x[((n * 3 + ci) * IH + iy) * IW + ix];
        Ts[(ci * 4 + ky) * 132 + xx] = v;
    }
    __syncthreads();
    int cog = tid & 31, pxg = tid >> 5;
    int co0 = cog * 4, px0 = pxg * 8;
    float acc[8][4];
#pragma unroll
    for (int i = 0; i < 8; ++i)
#pragma unroll
        for (int j = 0; j < 4; ++j) acc[i][j] = 0.f;
#pragma unroll 1
    for (int ky = 0; ky < 4; ++ky)
#pragma unroll 1
        for (int kx = 0; kx < 4; ++kx)
#pragma unroll
            for (int ci = 0; ci < 3; ++ci) {
                float4 b = *(const float4*)&Bs[((ky * 4 + kx) * 3 + ci) * 128 + co0];
                const float* trow = &Ts[(ci * 4 + ky) * 132 + kx];
#pragma unroll
                for (int q = 0; q < 8; ++q) {
                    float a = trow[2 * (px0 + q)];
                    acc[q][0] = fmaf(a, b.x, acc[q][0]);
                    acc[q][1] = fmaf(a, b.y, acc[q][1]);
                    acc[q][2] = fmaf(a, b.z, acc[q][2]);
                    acc[q][3] = fmaf(a, b.w, acc[q][3]);
                }
            }
    float4 bb = *(const float4*)&bias[co0];
#pragma unroll
    for (int q = 0; q < 8; ++q) {
        int ox = ox0 + px0 + q;
        float v0 = fmaxf(acc[q][0] + bb.x, 0.f);
        float v1 = fmaxf(acc[q][1] + bb.y, 0.f);
        float v2 = fmaxf(acc[q][2] + bb.z, 0.f);
        float v3 = fmaxf(acc[q][3] + bb.w, 0.f);
        unsigned h0, l0, h1, l1;
        cvt_split2(v0, v1, h0, l0);
        cvt_split2(v2, v3, h1, l1);
        long pix = ((long)n * OH + oy) * OW + ox;
        *(uint2*)&outb[pix * 128 + co0]        = make_uint2(h0, h1);
        *(uint2*)&outb[APL0 + pix * 128 + co0] = make_uint2(l0, l1);
    }
}

// ---------------------------------------------------------------------------
__global__ void enorm_kernel(const float* __restrict__ et, const float* __restrict__ eb,
                             float* __restrict__ nt, float* __restrict__ nb) {
    int k = blockIdx.x * TPB + threadIdx.x;
    if (k >= 1024) return;
    const float* e = (k < 512) ? et : eb;
    float* o = (k < 512) ? nt : nb;
    int kk = k & 511;
    float s = 0.f;
#pragma unroll 8
    for (int d = 0; d < 64; ++d) { float v = e[d * 512 + kk]; s = fmaf(v, v, s); }
    o[kk] = s;
}

// ---------------------------------------------------------------------------
// MFMA vector quantize.  Emits fp32 qn + plain bf16 qnb; qc NCHW; one
// atomicAdd per block.
// ---------------------------------------------------------------------------
__global__ __launch_bounds__(256) void quantize_mfma(
    const float* __restrict__ f, const short* __restrict__ ET,
    const float* __restrict__ embed, const float* __restrict__ enorm,
    float* __restrict__ qn, short* __restrict__ qnb, float* __restrict__ qc,
    float* __restrict__ ido, float* __restrict__ dsum, int M, int HW) {
    __shared__ short Fh[64 * 72];
    __shared__ short Fl[64 * 72];
    __shared__ float S[64 * 65];
    __shared__ int   KI[64];
    __shared__ float wsum[4];

    const int tid = threadIdx.x;
    const int lane = tid & 63, wv = tid >> 6;
    const int quad = lane >> 4, l16 = lane & 15;
    const int R0 = blockIdx.x * 64;

    {
        int row = tid >> 2;
        int k0 = (tid & 3) * 16;
        const float* sp = f + (long)(R0 + row) * 64 + k0;
        unsigned hw[8], lw[8];
#pragma unroll
        for (int i = 0; i < 4; ++i) {
            float4 p = *(const float4*)(sp + 4 * i);
            cvt_split2(p.x, p.y, hw[2 * i], lw[2 * i]);
            cvt_split2(p.z, p.w, hw[2 * i + 1], lw[2 * i + 1]);
        }
        short* dh = &Fh[row * 72 + k0];
        short* dl = &Fl[row * 72 + k0];
        *(uint4*)(dh)     = make_uint4(hw[0], hw[1], hw[2], hw[3]);
        *(uint4*)(dh + 8) = make_uint4(hw[4], hw[5], hw[6], hw[7]);
        *(uint4*)(dl)     = make_uint4(lw[0], lw[1], lw[2], lw[3]);
        *(uint4*)(dl + 8) = make_uint4(lw[4], lw[5], lw[6], lw[7]);
    }
    __syncthreads();

    const int arow = (wv * 16 + l16) * 72;
    bf16x8 Ah0 = *(const bf16x8*)&Fh[arow + quad * 8];
    bf16x8 Ah1 = *(const bf16x8*)&Fh[arow + 32 + quad * 8];
    bf16x8 Al0 = *(const bf16x8*)&Fl[arow + quad * 8];
    bf16x8 Al1 = *(const bf16x8*)&Fl[arow + 32 + quad * 8];

    float bestv[4];
    int   besti[4];
#pragma unroll
    for (int r = 0; r < 4; ++r) { bestv[r] = 3.4e38f; besti[r] = 0; }

    const short* ETlo = ET + 32768;
#pragma unroll 2
    for (int j = 0; j < 32; ++j) {
        const int nb = (j * 16 + l16) * 64 + quad * 8;
        bf16x8 Bh0 = *(const bf16x8*)(ET + nb);
        bf16x8 Bh1 = *(const bf16x8*)(ET + nb + 32);
        bf16x8 Bl0 = *(const bf16x8*)(ETlo + nb);
        bf16x8 Bl1 = *(const bf16x8*)(ETlo + nb + 32);
        f32x4 acc = f32x4{0.f, 0.f, 0.f, 0.f};
        acc = __builtin_amdgcn_mfma_f32_16x16x32_bf16(Ah0, Bh0, acc, 0, 0, 0);
        acc = __builtin_amdgcn_mfma_f32_16x16x32_bf16(Ah1, Bh1, acc, 0, 0, 0);
        acc = __builtin_amdgcn_mfma_f32_16x16x32_bf16(Al0, Bh0, acc, 0, 0, 0);
        acc = __builtin_amdgcn_mfma_f32_16x16x32_bf16(Al1, Bh1, acc, 0, 0, 0);
        acc = __builtin_amdgcn_mfma_f32_16x16x32_bf16(Ah0, Bl0, acc, 0, 0, 0);
        acc = __builtin_amdgcn_mfma_f32_16x16x32_bf16(Ah1, Bl1, acc, 0, 0, 0);
        float en = enorm[j * 16 + l16];
        int   ni = j * 16 + l16;
#pragma unroll
        for (int r = 0; r < 4; ++r) {
            float s = fmaf(-2.f, acc[r], en);
            if (s < bestv[r]) { bestv[r] = s; besti[r] = ni; }
        }
    }
#pragma unroll
    for (int m = 1; m < 16; m <<= 1) {
#pragma unroll
        for (int r = 0; r < 4; ++r) {
            float ov = __shfl_xor(bestv[r], m);
            int   oi = __shfl_xor(besti[r], m);
            if (ov < bestv[r] || (ov == bestv[r] && oi < besti[r])) {
                bestv[r] = ov; besti[r] = oi;
            }
        }
    }
    if (l16 == 0) {
#pragma unroll
        for (int r = 0; r < 4; ++r) KI[wv * 16 + quad * 4 + r] = besti[r];
    }
    __syncthreads();

    float ddacc = 0.f;
#pragma unroll 1
    for (int r16 = 0; r16 < 16; ++r16) {
        int row = wv * 16 + r16;
        int k = KI[row];
        float ev = embed[lane * 512 + k];
        float fv = f[(long)(R0 + row) * 64 + lane];
        long qi = (long)(R0 + row) * 64 + lane;
        qn[qi] = ev;
        qnb[qi] = (short)bf16_rne(ev);
        S[row * 65 + lane] = ev;
        float dq = ev - fv;
        ddacc = fmaf(dq, dq, ddacc);
        if (lane == 0) ido[R0 + row] = (float)k;
    }
#pragma unroll
    for (int off = 1; off < 64; off <<= 1) ddacc += __shfl_xor(ddacc, off);
    if (lane == 0) wsum[wv] = ddacc;
    __syncthreads();
    if (tid == 0)
        atomicAdd(dsum, wsum[0] + wsum[1] + wsum[2] + wsum[3]);

    int nn = R0 / HW;
    int rem0 = R0 - nn * HW;
    int px = tid & 63;
    int cg = tid >> 6;
#pragma unroll
    for (int it = 0; it < 16; ++it) {
        int c = cg + 4 * it;
        qc[((long)nn * 64 + c) * HW + rem0 + px] = S[px * 65 + c];
    }
}

// ---------------------------------------------------------------------------
// ECAT concat: [DECT fp32 64ch | T1B split-bf16 reconstructed 128ch] -> fp32
// ---------------------------------------------------------------------------
__global__ void concat_rec_kernel(const float* __restrict__ a, const short* __restrict__ bh,
                                  float* __restrict__ o, int M) {
    const long PLB = 8388608L;   // 16*64*64*128
    int idx = blockIdx.x * TPB + threadIdx.x;
    if (idx >= M * 48) return;
    int row = idx / 48;
    int c4  = (idx - row * 48) * 4;
    float4 v;
    if (c4 < 64) v = *(const float4*)(a + (long)row * 64 + c4);
    else {
        int cc = c4 - 64;
        uint2 h = *(const uint2*)(bh + (long)row * 128 + cc);
        uint2 l = *(const uint2*)(bh + PLB + (long)row * 128 + cc);
        v.x = __uint_as_float(h.x << 16)         + __uint_as_float(l.x << 16);
        v.y = __uint_as_float(h.x & 0xFFFF0000u) + __uint_as_float(l.x & 0xFFFF0000u);
        v.z = __uint_as_float(h.y << 16)         + __uint_as_float(l.y << 16);
        v.w = __uint_as_float(h.y & 0xFFFF0000u) + __uint_as_float(l.y & 0xFFFF0000u);
    }
    *(float4*)(o + (long)row * 192 + c4) = v;
}

// ---------------------------------------------------------------------------
// QCAT concat (plain bf16): ch0-63 = cvt(UPT fp32), ch64-127 = QBNB copy.
// ---------------------------------------------------------------------------
__global__ void concat_qcat_kernel(const float* __restrict__ a, const short* __restrict__ qh,
                                   short* __restrict__ o, int M) {
    int idx = blockIdx.x * TPB + threadIdx.x;
    if (idx >= M * 32) return;
    int row = idx / 32;
    int c4  = (idx - row * 32) * 4;
    uint2 w;
    if (c4 < 64) {
        float4 v = *(const float4*)(a + (long)row * 64 + c4);
        w = make_uint2(cvt_pk(v.x, v.y), cvt_pk(v.z, v.w));
    } else {
        w = *(const uint2*)(qh + (long)row * 64 + (c4 - 64));
    }
    *(uint2*)(o + (long)row * 128 + c4) = w;
}

// ---------------------------------------------------------------------------
__global__ void loss_kernel(const float* __restrict__ sums, float* __restrict__ out) {
    out[0] = sums[0] * (1.f / (16384.f * 64.f)) + sums[1] * (1.f / (65536.f * 64.f));
}

// ---------------------------------------------------------------------------
extern "C" void kernel_launch(void* const* d_in, const int* in_sizes, int n_in,
                              void* d_out, int out_size, void* d_ws, size_t ws_size,
                              hipStream_t stream) {
    const float* x   = (const float*)d_in[0];
    const float* wb1 = (const float*)d_in[1];  const float* bb1 = (const float*)d_in[2];
    const float* wb2 = (const float*)d_in[3];  const float* bb2 = (const float*)d_in[4];
    const float* wt1 = (const float*)d_in[5];  const float* bt1 = (const float*)d_in[6];
    const float* wqt = (const float*)d_in[7];  const float* bqt = (const float*)d_in[8];
    const float* embed_t = (const float*)d_in[9];
    const float* wdt = (const float*)d_in[10]; const float* bdt = (const float*)d_in[11];
    const float* wqb = (const float*)d_in[12]; const float* bqb = (const float*)d_in[13];
    const float* embed_b = (const float*)d_in[14];
    const float* wup = (const float*)d_in[15]; const float* bup = (const float*)d_in[16];
    const float* wd1 = (const float*)d_in[17]; const float* bd1 = (const float*)d_in[18];
    const float* wd2 = (const float*)d_in[19]; const float* bd2 = (const float*)d_in[20];
    float* out = (float*)d_out;
    float* ws  = (float*)d_ws;

    float* O_XHAT = out;
    float* O_QT   = out + 3145728;
    float* O_QB   = out + 4194304;
    float* O_LOSS = out + 8388608;
    float* O_IDT  = out + 8388609;
    float* O_IDB  = out + 8404993;

    // ws layout (float-slot offsets)
    float* W_WB1  = ws + 0;                    // 6144 fp32 (conv1)
    short* WB_WD2 = (short*)(ws + 16384);      // 16384 sh
    short* ET_T   = (short*)(ws + 32768);      // 65536 sh
    short* ET_B   = (short*)(ws + 65536);      // 65536 sh
    short* WB_WQT = (short*)(ws + 98304);      // 16384 sh (split 1x1 128->64)
    float* W_WDT  = ws + 540672;               // 65536 fp32 (exact convT 64->64)
    float* W_WQB  = ws + 606208;               // 12288 fp32 (exact 1x1 192->64)
    float* EN_T  = ws + 818176;
    float* EN_B  = ws + 818688;
    float* SUMS  = ws + 819200;
    short* T1B   = (short*)(ws + 1048576);     // split [2][16,64,64,128]
    const long BIG = 9437184;
    short* T0B   = (short*)(ws + BIG);         // split [2][16,128,128,128]
    short* T2B   = (short*)(ws + BIG);         // split [2][16,32,32,128] (T0B dead)
    float* QT    = ws + BIG + 2097152;         // fp32 [16384,64]
    float* QTN   = ws + BIG + 3145728;         // fp32 quant_t rows (for wdt)
    short* QTNB  = (short*)(ws + BIG + 4194304);  // plain bf16 (for wup)
    float* DECT  = ws + BIG + 4718592;         // fp32 [16,64,64,64]
    float* ECAT  = ws + BIG + 8912896;         // fp32 [16,64,64,192]
    float* QB    = ws + BIG + 21495808;        // fp32 [65536,64]
    short* QBNB  = (short*)(ws + BIG + 25690112); // plain bf16 [65536,64]
    float* QND   = ws + BIG + 27787264;        // fp32 dump (bottom qn, unused)
    float* UPT   = ws + BIG + 4718592;         // fp32, reuses DECT
    short* QCATB = (short*)(ws + BIG + 8912896);  // plain bf16, reuses ECAT
    short* HBUFB = (short*)(ws + BIG + 16777216); // plain bf16 [16,128,128,64]
    short* WB_BF2 = (short*)(ws + 42991616);
    short* WB_BT1 = (short*)(ws + 43253760);
    short* WB_BD1 = (short*)(ws + 43515904);
    short* WB_BUP = (short*)(ws + 43646976);

    auto wt_launch = [&](const float* src, float* dst, int cin, int cout, int taps, int iohw) {
        int tot = cin * cout * taps;
        wtrans_kernel<<<(tot + TPB - 1) / TPB, TPB, 0, stream>>>(src, dst, cin, cout, taps, iohw);
    };
    auto wtb_launch = [&](const float* src, short* dst, int cin, int cout, int taps, int iohw) {
        int tot = cin * cout * taps;
        wtrans_bf16_kernel<<<(tot + TPB - 1) / TPB, TPB, 0, stream>>>(src, dst, cin, cout, taps, iohw, tot);
    };
    wt_launch(wb1, W_WB1, 3, 128, 16, 0);
    wt_launch(wdt, W_WDT, 64, 64, 16, 1);
    wt_launch(wqb, W_WQB, 192, 64, 1, 0);
    wtrans_wd2_kernel<<<64, TPB, 0, stream>>>(wd2, WB_WD2);
    wtb_launch(wb2, WB_BF2, 128, 128, 16, 0);
    wtb_launch(wt1, WB_BT1, 128, 128, 16, 0);
    wtb_launch(wqt, WB_WQT, 128, 64, 1, 0);
    wtb_launch(wd1, WB_BD1, 128, 64, 16, 1);
    wtb_launch(wup, WB_BUP, 64, 64, 16, 1);
    enorm_kernel<<<4, TPB, 0, stream>>>(embed_t, embed_b, EN_T, EN_B);
    etrans_kernel<<<256, TPB, 0, stream>>>(embed_t, embed_b, ET_T, ET_B);
    hipError_t e0 = hipMemsetAsync((void*)SUMS, 0, 2 * sizeof(float), stream);
    (void)e0;

    // ----- encode -----
    conv1_kernel<<<4096, TPB, 0, stream>>>(x, W_WB1, bb1, T0B);
    // conv2: split in/out, KR=32, NSP=2 with same-XCD co-pairing
    mfma_conv<0, 128, 128, 1, 1, 128, 128, 64, 64, 2, 1, 3, 32, 2>
        <<<1024, TPB, 0, stream>>>(T0B, WB_BF2, bb2, nullptr, T1B);
    // conv3: split in/out, NSP=2 with same-XCD co-pairing
    mfma_conv<0, 128, 128, 1, 1, 64, 64, 32, 32, 4, 1, 3, 32, 2>
        <<<256, TPB, 0, stream>>>(T1B, WB_BT1, bt1, nullptr, T2B);
    // wqt 1x1: split MFMA, fp32 out
    mfma_conv<2, 128, 64, 1, 0, 32, 32, 32, 32, 4, 1, 0, 64, 1>
        <<<128, TPB, 0, stream>>>(T2B, WB_WQT, bqt, QT, nullptr);
    quantize_mfma<<<256, TPB, 0, stream>>>(QT, ET_T, embed_t, EN_T, QTN, QTNB,
                                           O_QT, O_IDT, SUMS, 16384, 1024);
    // wdt: fp32 exact (id_b-critical)
    conv_gemm<1, 64, 64, 32, 0, 32, 32, 64, 64><<<2048, TPB, 0, stream>>>(QTN, W_WDT, bdt, DECT);
    concat_rec_kernel<<<12288, TPB, 0, stream>>>(DECT, T1B, ECAT, 65536);
    // wqb: fp32 exact (id_b-critical)
    conv_gemm<2, 192, 64, 64, 0, 64, 64, 64, 64><<<1024, TPB, 0, stream>>>(ECAT, W_WQB, bqb, QB);
    quantize_mfma<<<1024, TPB, 0, stream>>>(QB, ET_B, embed_b, EN_B, QND, QBNB,
                                            O_QB, O_IDB, SUMS + 1, 65536, 4096);
    // ----- decode -----
    // wup: plain bf16 in (QTNB), KR=64, fp32 out
    mfma_conv<1, 64, 64, 0, 0, 32, 32, 64, 64, 4, 1, 0, 64, 1>
        <<<512, TPB, 0, stream>>>(QTNB, WB_BUP, bup, UPT, nullptr);
    concat_qcat_kernel<<<8192, TPB, 0, stream>>>(UPT, QBNB, QCATB, 65536);
    // dec1: plain bf16 in, KR=64, plain bf16 out + ReLU
    mfma_conv<1, 128, 64, 0, 1, 64, 64, 128, 128, 2, 1, 2, 64, 1>
        <<<2048, TPB, 0, stream>>>(QCATB, WB_BD1, bd1, nullptr, HBUFB);
    convt_final_mfma<<<2048, TPB, 0, stream>>>(HBUFB, WB_WD2, bd2, O_XHAT);
    loss_kernel<<<1, 1, 0, stream>>>(SUMS, O_LOSS);

    (void)in_sizes; (void)n_in; (void)out_size; (void)ws_size;
}

// Round 12
// 702.484 us; speedup vs baseline: 1.1635x; 1.0232x over previous
//
#include <hip/hip_runtime.h>

#define TPB 256

typedef __attribute__((ext_vector_type(4))) float f32x4;
typedef __attribute__((ext_vector_type(8))) short bf16x8;

// ---------------------------------------------------------------------------
// Weight transform fp32: src OIHW (iohw=0) or IOHW (iohw=1) -> [tap][ci][co]
// ---------------------------------------------------------------------------
__global__ void wtrans_kernel(const float* __restrict__ src, float* __restrict__ dst,
                              int CIN, int COUT, int taps, int iohw) {
    int idx = blockIdx.x * TPB + threadIdx.x;
    int tot = CIN * COUT * taps;
    if (idx >= tot) return;
    int co = idx % COUT;
    int ci = (idx / COUT) % CIN;
    int tap = idx / (COUT * CIN);
    float v = iohw ? src[(ci * COUT + co) * taps + tap]
                   : src[(co * CIN + ci) * taps + tap];
    dst[idx] = v;
}

// ---------------------------------------------------------------------------
__device__ __forceinline__ unsigned bf16_rne(float v) {
    unsigned u = __float_as_uint(v);
    return (u + 0x7FFFu + ((u >> 16) & 1u)) >> 16;
}

// ---------------------------------------------------------------------------
// Weight transform bf16-split: fp32 -> hi plane [tap][co][ci], lo at +PL.
// ---------------------------------------------------------------------------
__global__ void wtrans_bf16_kernel(const float* __restrict__ src, short* __restrict__ dst,
                                   int CIN, int COUT, int taps, int iohw, int PL) {
    int idx = blockIdx.x * TPB + threadIdx.x;
    int tot = CIN * COUT * taps;
    if (idx >= tot) return;
    int ci = idx % CIN;
    int co = (idx / CIN) % COUT;
    int tap = idx / (CIN * COUT);
    float v = iohw ? src[(ci * COUT + co) * taps + tap]
                   : src[(co * CIN + ci) * taps + tap];
    unsigned h = bf16_rne(v);
    float rem = v - __uint_as_float(h << 16);
    dst[idx] = (short)h;
    dst[idx + PL] = (short)bf16_rne(rem);
}

// ---------------------------------------------------------------------------
// wd2 weights -> bf16 [cls(4)][tap(4)][co(16 pad from 3)][ci(64)]
// ---------------------------------------------------------------------------
__global__ void wtrans_wd2_kernel(const float* __restrict__ src, short* __restrict__ dst) {
    int idx = blockIdx.x * TPB + threadIdx.x;
    if (idx >= 16384) return;
    int ci  = idx & 63;
    int co  = (idx >> 6) & 15;
    int tap = (idx >> 10) & 3;
    int cls = idx >> 12;
    int py = cls >> 1, px = cls & 1;
    int jj = tap >> 1, ii = tap & 1;
    int ky = (1 - py) + 2 * jj;
    int kx = (1 - px) + 2 * ii;
    float v = (co < 3) ? src[(ci * 3 + co) * 16 + ky * 4 + kx] : 0.f;
    dst[idx] = (short)bf16_rne(v);
}

// ---------------------------------------------------------------------------
// embed [64,512] fp32 -> transposed split bf16 [n=512][k=64], hi | lo planes.
// ---------------------------------------------------------------------------
__global__ void etrans_kernel(const float* __restrict__ et, const float* __restrict__ eb,
                              short* __restrict__ ETt, short* __restrict__ ETb) {
    int idx = blockIdx.x * TPB + threadIdx.x;
    if (idx >= 65536) return;
    const float* src = (idx < 32768) ? et : eb;
    short* dst = (idx < 32768) ? ETt : ETb;
    int i = idx & 32767;
    int k = i & 63;
    int n = i >> 6;
    float v = src[k * 512 + n];
    unsigned h = bf16_rne(v);
    float rem = v - __uint_as_float(h << 16);
    dst[i] = (short)h;
    dst[i + 32768] = (short)bf16_rne(rem);
}

// ---------------------------------------------------------------------------
__device__ __forceinline__ void cvt_split2(float a, float b, unsigned& hw, unsigned& lw) {
    unsigned ha = bf16_rne(a), hb = bf16_rne(b);
    float ra = a - __uint_as_float(ha << 16);
    float rb = b - __uint_as_float(hb << 16);
    hw = ha | (hb << 16);
    lw = bf16_rne(ra) | (bf16_rne(rb) << 16);
}
__device__ __forceinline__ unsigned cvt_pk(float a, float b) {
    return bf16_rne(a) | (bf16_rne(b) << 16);
}

// ---------------------------------------------------------------------------
// MFMA implicit-GEMM conv.  bf16(-split) compute; staging is uint4 copy when
// INBF=1.  MODE 0: 4x4 s2 p1 conv.  MODE 1: convT (4 parity classes).
// MODE 2: 1x1.  OUTB: 0 = fp32; 2 = plain bf16; 3 = split bf16.
// KR: K per barrier round.  NSP: co-split factor.  For NSP=2 the co-half is
// taken from bit 3 of blockIdx so the two halves of one spatial tile land on
// the SAME XCD (bx%8 round-robin, measured R10->R11: FETCH 786->264 MB)
// adjacent in XCD-local order.  Grid must be divisible by 16 when NSP=2.
// Plain row*ST+koff LDS layout (XOR swizzle measured WORSE in R10/R11).
// ---------------------------------------------------------------------------
template<int MODE, int CIN, int COUT, int SPLIT, int RELU,
         int IH, int IW, int OH, int OW, int R, int INBF, int OUTB, int KR, int NSP>
__global__ __launch_bounds__(256) void mfma_conv(
    const void* __restrict__ inv, const short* __restrict__ Wb,
    const float* __restrict__ bias, float* __restrict__ outp,
    short* __restrict__ outb) {
    constexpr int TAPS = (MODE == 0) ? 16 : (MODE == 1 ? 4 : 1);
    constexpr int CW = (MODE == 1) ? OW / 2 : OW;
    constexpr int CH = (MODE == 1) ? OH / 2 : OH;
    constexpr int NCOUT = COUT / NSP;           // logical cout per block
    constexpr int NRND = CIN / KR;
    constexpr int KC = KR / 32;
    constexpr int ST = KR + 8;
    constexpr int MTc = (NCOUT == 128) ? 4 : 2;
    constexpr long PLW = (long)TAPS * COUT * CIN;
    constexpr long APL_IN  = 16L * IH * IW * CIN;
    constexpr long APL_OUT = 16L * OH * OW * COUT;
    constexpr int NU4A = KR / 16;
    constexpr int TPR  = 256 / NCOUT;
    constexpr int SPT  = KR / TPR;
    constexpr int NU4B = SPT / 8;

    __shared__ short Ah[128 * ST];
    __shared__ short Al[SPLIT ? 128 * ST : 8];
    __shared__ short Bh[NCOUT * ST];
    __shared__ short Bl[SPLIT ? NCOUT * ST : 8];

    int bx = blockIdx.x;
    int co_off = 0;
    if (NSP == 2) {
        // co-half from bit 3: pairs (bx, bx+8) share spatial tile AND XCD.
        co_off = ((bx >> 3) & 1) * NCOUT;
        bx = (bx & 7) | ((bx >> 4) << 3);
    }
    int ry = 0, rx = 0;
    if (MODE == 1) { int c = bx & 3; ry = c >> 1; rx = c & 1; bx >>= 2; }
    const int y0 = (bx % (CH / R)) * R;
    const int n  = bx / (CH / R);

    const int tid = threadIdx.x;
    const int p   = tid >> 1;
    const int akb = (tid & 1) * (KR / 2);
    const int rr = p / CW, xx = p % CW;
    const int bco = tid / TPR;
    const int bk  = (tid % TPR) * SPT;
    const int lane = tid & 63, wv = tid >> 6;
    const int quad = lane >> 4, l16 = lane & 15;
    const int mbase = (NCOUT == 128) ? (wv & 1) * 64 : wv * 32;
    const int nbase = (NCOUT == 128) ? (wv >> 1) * 64 : 0;

    f32x4 acc[MTc][4];
#pragma unroll
    for (int mt = 0; mt < MTc; ++mt)
#pragma unroll
        for (int nt = 0; nt < 4; ++nt) acc[mt][nt] = f32x4{0.f, 0.f, 0.f, 0.f};

#pragma unroll 1
    for (int tap = 0; tap < TAPS; ++tap) {
        int iy, ix, wt;
        if (MODE == 0) {
            int ky = tap >> 2, kx = tap & 3;
            iy = 2 * (y0 + rr) - 1 + ky;
            ix = 2 * xx - 1 + kx;
            wt = tap;
        } else if (MODE == 1) {
            int jj = tap >> 1, ii = tap & 1;
            iy = (y0 + rr) + ry - jj;
            ix = xx + rx - ii;
            wt = ((1 - ry) + 2 * jj) * 4 + ((1 - rx) + 2 * ii);
        } else {
            iy = y0 + rr; ix = xx; wt = 0;
        }
        const bool av = (MODE == 2) ||
                        ((iy >= 0) && (iy < IH) && (ix >= 0) && (ix < IW));
        const long abase = ((long)(n * IH + iy) * IW + ix) * CIN + akb;

#pragma unroll 1
        for (int ko = 0; ko < NRND; ++ko) {
            __syncthreads();
            if constexpr (INBF) {
                const short* sb = (const short*)inv + abase + ko * KR;
#pragma unroll
                for (int u = 0; u < NU4A; ++u) {
                    uint4 h = av ? *(const uint4*)(sb + 8 * u) : make_uint4(0, 0, 0, 0);
                    *(uint4*)&Ah[p * ST + akb + 8 * u] = h;
                }
                if constexpr (SPLIT) {
#pragma unroll
                    for (int u = 0; u < NU4A; ++u) {
                        uint4 l = av ? *(const uint4*)(sb + APL_IN + 8 * u) : make_uint4(0, 0, 0, 0);
                        *(uint4*)&Al[p * ST + akb + 8 * u] = l;
                    }
                }
            } else {
                const float* sp = (const float*)inv + abase + ko * KR;
#pragma unroll
                for (int u = 0; u < NU4A; ++u) {
                    float4 f0, f1;
                    if (av) { f0 = *(const float4*)(sp + 8 * u); f1 = *(const float4*)(sp + 8 * u + 4); }
                    else { f0.x=f0.y=f0.z=f0.w=0.f; f1 = f0; }
                    unsigned h0, l0, h1, l1, h2, l2, h3, l3;
                    cvt_split2(f0.x, f0.y, h0, l0); cvt_split2(f0.z, f0.w, h1, l1);
                    cvt_split2(f1.x, f1.y, h2, l2); cvt_split2(f1.z, f1.w, h3, l3);
                    *(uint4*)&Ah[p * ST + akb + 8 * u] = make_uint4(h0, h1, h2, h3);
                    if constexpr (SPLIT)
                        *(uint4*)&Al[p * ST + akb + 8 * u] = make_uint4(l0, l1, l2, l3);
                }
            }
            {
                const short* wr = Wb + ((long)wt * COUT + co_off + bco) * CIN + ko * KR + bk;
#pragma unroll
                for (int u = 0; u < NU4B; ++u) {
                    *(uint4*)&Bh[bco * ST + bk + 8 * u] = *(const uint4*)(wr + 8 * u);
                    if constexpr (SPLIT)
                        *(uint4*)&Bl[bco * ST + bk + 8 * u] = *(const uint4*)(wr + PLW + 8 * u);
                }
            }
            __syncthreads();
#pragma unroll
            for (int kc = 0; kc < KC; ++kc) {
                bf16x8 ahf[MTc], alf[SPLIT ? MTc : 1];
#pragma unroll
                for (int mt = 0; mt < MTc; ++mt) {
                    int mrow = mbase + mt * 16 + l16;
                    ahf[mt] = *(const bf16x8*)&Ah[mrow * ST + kc * 32 + quad * 8];
                    if constexpr (SPLIT)
                        alf[mt] = *(const bf16x8*)&Al[mrow * ST + kc * 32 + quad * 8];
                }
#pragma unroll
                for (int nt = 0; nt < 4; ++nt) {
                    int nrow = nbase + nt * 16 + l16;
                    bf16x8 bhf = *(const bf16x8*)&Bh[nrow * ST + kc * 32 + quad * 8];
#pragma unroll
                    for (int mt = 0; mt < MTc; ++mt)
                        acc[mt][nt] = __builtin_amdgcn_mfma_f32_16x16x32_bf16(ahf[mt], bhf, acc[mt][nt], 0, 0, 0);
                    if constexpr (SPLIT) {
                        bf16x8 blf = *(const bf16x8*)&Bl[nrow * ST + kc * 32 + quad * 8];
#pragma unroll
                        for (int mt = 0; mt < MTc; ++mt) {
                            acc[mt][nt] = __builtin_amdgcn_mfma_f32_16x16x32_bf16(alf[mt], bhf, acc[mt][nt], 0, 0, 0);
                            acc[mt][nt] = __builtin_amdgcn_mfma_f32_16x16x32_bf16(ahf[mt], blf, acc[mt][nt], 0, 0, 0);
                        }
                    }
                }
            }
        }
    }
#pragma unroll
    for (int mt = 0; mt < MTc; ++mt)
#pragma unroll
        for (int nt = 0; nt < 4; ++nt) {
            int co = co_off + nbase + nt * 16 + l16;
            float bv = bias[co];
#pragma unroll
            for (int r = 0; r < 4; ++r) {
                int pl = mbase + mt * 16 + quad * 4 + r;
                int rr2 = pl / CW, x2 = pl % CW;
                int oy, ox;
                if (MODE == 1) { oy = 2 * (y0 + rr2) + ry; ox = 2 * x2 + rx; }
                else           { oy = y0 + rr2; ox = x2; }
                float vv = acc[mt][nt][r] + bv;
                if (RELU) vv = fmaxf(vv, 0.f);
                long oidx = ((long)(n * OH + oy) * OW + ox) * COUT + co;
                if constexpr (OUTB == 0) outp[oidx] = vv;
                if constexpr (OUTB == 3) {
                    unsigned hh = bf16_rne(vv);
                    outb[oidx] = (short)hh;
                    outb[oidx + APL_OUT] = (short)bf16_rne(vv - __uint_as_float(hh << 16));
                }
                if constexpr (OUTB == 2) outb[oidx] = (short)bf16_rne(vv);
            }
        }
}

// ---------------------------------------------------------------------------
// Generic fp32 tiled conv-as-GEMM (wdt / wqb — id-critical exact path).
// ---------------------------------------------------------------------------
template<int MODE, int CIN, int COUT, int BM, int RELU, int IH, int IW, int OH, int OW>
__global__ __launch_bounds__(256) void conv_gemm(
    const float* __restrict__ in, const float* __restrict__ Wt,
    const float* __restrict__ bias, float* __restrict__ out) {
    constexpr int CHUNK  = 64;
    constexpr int NCH    = CIN / CHUNK;
    constexpr int CO_PER = (COUT == 128) ? 4 : 2;
    constexpr int PX_PER = BM / 8;
    constexpr int TAPS   = (MODE == 0) ? 16 : (MODE == 1 ? 4 : 1);
    __shared__ float As[CHUNK * BM];
    __shared__ float Bs[CHUNK * COUT];
    const int tid = threadIdx.x;
    const int bx  = blockIdx.x;
    int n, oy, ox0 = 0, par = 0;
    if (MODE == 1) {
        par = bx & 1;
        oy  = (bx >> 1) % OH;
        n   = bx / (2 * OH);
    } else {
        constexpr int SPR = OW / BM;
        int s = bx % SPR;
        oy = (bx / SPR) % OH;
        n  = bx / (SPR * OH);
        ox0 = s * BM;
    }
    const int cog = tid & 31;
    const int pxg = tid >> 5;
    const int co0 = cog * CO_PER, px0 = pxg * PX_PER;
    float acc[PX_PER][CO_PER];
#pragma unroll
    for (int q = 0; q < PX_PER; ++q)
#pragma unroll
        for (int j = 0; j < CO_PER; ++j) acc[q][j] = 0.f;
    constexpr int TPX  = 256 / BM;
    constexpr int CIPT = CHUNK / TPX;
    const int spx  = tid / TPX;
    const int sci0 = (tid % TPX) * CIPT;
    const int py   = oy & 1;

#pragma unroll 1
    for (int tap = 0; tap < TAPS; ++tap) {
        int iy, twi, sx;
        if (MODE == 0) {
            int ky = tap >> 2, kx = tap & 3;
            iy  = 2 * oy - 1 + ky;
            sx  = 2 * (ox0 + spx) - 1 + kx;
            twi = tap;
        } else if (MODE == 1) {
            int jj = tap >> 1, ii = tap & 1;
            iy  = ((oy + 1) >> 1) - jj;
            sx  = spx + par - ii;
            twi = ((1 - py) + 2 * jj) * 4 + ((1 - par) + 2 * ii);
        } else {
            iy = oy; sx = ox0 + spx; twi = 0;
        }
        const bool pxv = (iy >= 0) && (iy < IH) && (sx >= 0) && (sx < IW);
        const float* srcp = in + (((long)n * IH + iy) * IW + sx) * CIN + sci0;
#pragma unroll 1
        for (int cb = 0; cb < NCH; ++cb) {
            __syncthreads();
            float4 tmp[CIPT / 4];
#pragma unroll
            for (int t4 = 0; t4 < CIPT / 4; ++t4) {
                if (pxv) tmp[t4] = *(const float4*)(srcp + cb * CHUNK + 4 * t4);
                else { tmp[t4].x = 0.f; tmp[t4].y = 0.f; tmp[t4].z = 0.f; tmp[t4].w = 0.f; }
            }
#pragma unroll
            for (int t4 = 0; t4 < CIPT / 4; ++t4) {
                As[(sci0 + 4 * t4 + 0) * BM + spx] = tmp[t4].x;
                As[(sci0 + 4 * t4 + 1) * BM + spx] = tmp[t4].y;
                As[(sci0 + 4 * t4 + 2) * BM + spx] = tmp[t4].z;
                As[(sci0 + 4 * t4 + 3) * BM + spx] = tmp[t4].w;
            }
            {
                const float4* wsrc = (const float4*)(Wt + ((long)twi * CIN + cb * CHUNK) * COUT);
#pragma unroll
                for (int t4 = 0; t4 < (CHUNK * COUT) / 1024; ++t4)
                    ((float4*)Bs)[tid + 256 * t4] = wsrc[tid + 256 * t4];
            }
            __syncthreads();
#pragma unroll 4
            for (int k = 0; k < CHUNK; ++k) {
                float a[PX_PER];
#pragma unroll
                for (int t4 = 0; t4 < PX_PER / 4; ++t4)
                    *(float4*)&a[4 * t4] = *(const float4*)&As[k * BM + px0 + 4 * t4];
                if constexpr (CO_PER == 4) {
                    float4 b = *(const float4*)&Bs[k * COUT + co0];
#pragma unroll
                    for (int q = 0; q < PX_PER; ++q) {
                        acc[q][0] = fmaf(a[q], b.x, acc[q][0]);
                        acc[q][1] = fmaf(a[q], b.y, acc[q][1]);
                        acc[q][2] = fmaf(a[q], b.z, acc[q][2]);
                        acc[q][3] = fmaf(a[q], b.w, acc[q][3]);
                    }
                } else {
                    float2 b = *(const float2*)&Bs[k * COUT + co0];
#pragma unroll
                    for (int q = 0; q < PX_PER; ++q) {
                        acc[q][0] = fmaf(a[q], b.x, acc[q][0]);
                        acc[q][1] = fmaf(a[q], b.y, acc[q][1]);
                    }
                }
            }
        }
    }
    float bv[CO_PER];
#pragma unroll
    for (int j = 0; j < CO_PER; ++j) bv[j] = bias[co0 + j];
#pragma unroll
    for (int q = 0; q < PX_PER; ++q) {
        int ox = (MODE == 1) ? (par + 2 * (px0 + q)) : (ox0 + px0 + q);
        float* op = out + (((long)n * OH + oy) * OW + ox) * COUT + co0;
        if constexpr (CO_PER == 4) {
            float4 v;
            v.x = acc[q][0] + bv[0]; v.y = acc[q][1] + bv[1];
            v.z = acc[q][2] + bv[2]; v.w = acc[q][3] + bv[3];
            if (RELU) { v.x = fmaxf(v.x, 0.f); v.y = fmaxf(v.y, 0.f);
                        v.z = fmaxf(v.z, 0.f); v.w = fmaxf(v.w, 0.f); }
            *(float4*)op = v;
        } else {
            float2 v;
            v.x = acc[q][0] + bv[0]; v.y = acc[q][1] + bv[1];
            if (RELU) { v.x = fmaxf(v.x, 0.f); v.y = fmaxf(v.y, 0.f); }
            *(float2*)op = v;
        }
    }
}

// ---------------------------------------------------------------------------
// wd2 convT 64->3 via MFMA.  h plain bf16 [16,128,128,64].
// ---------------------------------------------------------------------------
__global__ __launch_bounds__(256) void convt_final_mfma(
    const short* __restrict__ h, const short* __restrict__ Wc,
    const float* __restrict__ bias, float* __restrict__ out) {
    const int HW = 128;
    __shared__ short HB[3 * 130 * 72];
    __shared__ float Sout[6 * 260];

    const int tid = threadIdx.x;
    const int y = blockIdx.x & 127;
    const int n = blockIdx.x >> 7;
    const int lane = tid & 63, wv = tid >> 6;
    const int quad = lane >> 4, l16 = lane & 15;

    for (int u = tid; u < 780; u += TPB) {
        int row = u >> 1, half = u & 1;
        int hr = row / 130, xc = row % 130;
        int hy = y - 1 + hr, hx = xc - 1;
        bool ok = (hy >= 0 && hy < HW && hx >= 0 && hx < HW);
        const short* sp = h + ((long)(n * HW + hy) * HW + hx) * 64 + half * 32;
        uint4 a0, a1, a2, a3;
        if (ok) {
            a0 = *(const uint4*)sp;        a1 = *(const uint4*)(sp + 8);
            a2 = *(const uint4*)(sp + 16); a3 = *(const uint4*)(sp + 24);
        } else {
            a0 = make_uint4(0,0,0,0); a1 = a0; a2 = a0; a3 = a0;
        }
        short* dp = &HB[row * 72 + half * 32];
        *(uint4*)dp = a0; *(uint4*)(dp + 8) = a1;
        *(uint4*)(dp + 16) = a2; *(uint4*)(dp + 24) = a3;
    }
    __syncthreads();

#pragma unroll 1
    for (int cls = 0; cls < 4; ++cls) {
        const int py = cls >> 1, px = cls & 1;
        bf16x8 Bf[4][2];
#pragma unroll
        for (int tap = 0; tap < 4; ++tap)
#pragma unroll
            for (int cb = 0; cb < 2; ++cb)
                Bf[tap][cb] = *(const bf16x8*)&Wc[((cls * 4 + tap) * 16 + l16) * 64 + cb * 32 + quad * 8];

        f32x4 acc2[2] = { f32x4{0.f,0.f,0.f,0.f}, f32x4{0.f,0.f,0.f,0.f} };
#pragma unroll
        for (int mt = 0; mt < 2; ++mt) {
            const int xp0 = wv * 32 + mt * 16;
#pragma unroll
            for (int tap = 0; tap < 4; ++tap) {
                const int jj = tap >> 1, ii = tap & 1;
                const int hr = py - jj + 1;
                const int rbase = (hr * 130 + xp0 + l16 + px - ii + 1) * 72;
#pragma unroll
                for (int cb = 0; cb < 2; ++cb) {
                    bf16x8 Af = *(const bf16x8*)&HB[rbase + cb * 32 + quad * 8];
                    acc2[mt] = __builtin_amdgcn_mfma_f32_16x16x32_bf16(Af, Bf[tap][cb], acc2[mt], 0, 0, 0);
                }
            }
        }
        if (l16 < 3) {
#pragma unroll
            for (int mt = 0; mt < 2; ++mt)
#pragma unroll
                for (int r = 0; r < 4; ++r) {
                    int xp = wv * 32 + mt * 16 + quad * 4 + r;
                    Sout[(py * 3 + l16) * 260 + 2 * xp + px] = acc2[mt][r];
                }
        }
    }
    __syncthreads();

    for (int u = tid; u < 384; u += TPB) {
        int idx = u * 4;
        int rowi = idx >> 8;
        int xq   = idx & 255;
        int py = rowi / 3, co = rowi % 3;
        float bv = bias[co];
        float4 v = *(const float4*)&Sout[rowi * 260 + xq];
        v.x += bv; v.y += bv; v.z += bv; v.w += bv;
        *(float4*)&out[(((long)(n * 3 + co) * 256) + 2 * y + py) * 256 + xq] = v;
    }
}

// ---------------------------------------------------------------------------
// conv1: x NCHW [16,3,256,256] -> split-bf16 NHWC [16,128,128,128] + ReLU
// ---------------------------------------------------------------------------
__global__ __launch_bounds__(256) void conv1_kernel(
    const float* __restrict__ x, const float* __restrict__ Wt,
    const float* __restrict__ bias, short* __restrict__ outb) {
    const int IH = 256, IW = 256, OH = 128, OW = 128, BM = 64;
    const long APL0 = 16L * 128 * 128 * 128;
    int bx = blockIdx.x;
    int sx = bx & 1;
    int oy = (bx >> 1) & 127;
    int n  = bx >> 8;
    int ox0 = sx * BM;
    __shared__ float Bs[16 * 3 * 128];
    __shared__ float Ts[3 * 4 * 132];
    int tid = threadIdx.x;
    for (int i = tid; i < 6144 / 4; i += TPB)
        ((float4*)Bs)[i] = ((const float4*)Wt)[i];
    int iy0 = 2 * oy - 1;
    for (int idx = tid; idx < 3 * 4 * 130; idx += TPB) {
        int ci = idx / 520; int r = idx % 520;
        int ky = r / 130;   int xx = r % 130;
        int iy = iy0 + ky;  int ix = 2 * ox0 - 1 + xx;
        float v = 0.f;
        if (iy >= 0 && iy < IH && ix >= 0 && ix < IW)
            v = x[((n * 3 + ci) * IH + iy) * IW + ix];
        Ts[(ci * 4 + ky) * 132 + xx] = v;
    }
    __syncthreads();
    int cog = tid & 31, pxg = tid >> 5;
    int co0 = cog * 4, px0 = pxg * 8;
    float acc[8][4];
#pragma unroll
    for (int i = 0; i < 8; ++i)
#pragma unroll
        for (int j = 0; j < 4; ++j) acc[i][j] = 0.f;
#pragma unroll 1
    for (int ky = 0; ky < 4; ++ky)
#pragma unroll 1
        for (int kx = 0; kx < 4; ++kx)
#pragma unroll
            for (int ci = 0; ci < 3; ++ci) {
                float4 b = *(const float4*)&Bs[((ky * 4 + kx) * 3 + ci) * 128 + co0];
                const float* trow = &Ts[(ci * 4 + ky) * 132 + kx];
#pragma unroll
                for (int q = 0; q < 8; ++q) {
                    float a = trow[2 * (px0 + q)];
                    acc[q][0] = fmaf(a, b.x, acc[q][0]);
                    acc[q][1] = fmaf(a, b.y, acc[q][1]);
                    acc[q][2] = fmaf(a, b.z, acc[q][2]);
                    acc[q][3] = fmaf(a, b.w, acc[q][3]);
                }
            }
    float4 bb = *(const float4*)&bias[co0];
#pragma unroll
    for (int q = 0; q < 8; ++q) {
        int ox = ox0 + px0 + q;
        float v0 = fmaxf(acc[q][0] + bb.x, 0.f);
        float v1 = fmaxf(acc[q][1] + bb.y, 0.f);
        float v2 = fmaxf(acc[q][2] + bb.z, 0.f);
        float v3 = fmaxf(acc[q][3] + bb.w, 0.f);
        unsigned h0, l0, h1, l1;
        cvt_split2(v0, v1, h0, l0);
        cvt_split2(v2, v3, h1, l1);
        long pix = ((long)n * OH + oy) * OW + ox;
        *(uint2*)&outb[pix * 128 + co0]        = make_uint2(h0, h1);
        *(uint2*)&outb[APL0 + pix * 128 + co0] = make_uint2(l0, l1);
    }
}

// ---------------------------------------------------------------------------
__global__ void enorm_kernel(const float* __restrict__ et, const float* __restrict__ eb,
                             float* __restrict__ nt, float* __restrict__ nb) {
    int k = blockIdx.x * TPB + threadIdx.x;
    if (k >= 1024) return;
    const float* e = (k < 512) ? et : eb;
    float* o = (k < 512) ? nt : nb;
    int kk = k & 511;
    float s = 0.f;
#pragma unroll 8
    for (int d = 0; d < 64; ++d) { float v = e[d * 512 + kk]; s = fmaf(v, v, s); }
    o[kk] = s;
}

// ---------------------------------------------------------------------------
// MFMA vector quantize.  Emits fp32 qn (optional, skipped when qn==nullptr)
// + plain bf16 qnb; qc NCHW; one atomicAdd per block.
// ---------------------------------------------------------------------------
__global__ __launch_bounds__(256) void quantize_mfma(
    const float* __restrict__ f, const short* __restrict__ ET,
    const float* __restrict__ embed, const float* __restrict__ enorm,
    float* __restrict__ qn, short* __restrict__ qnb, float* __restrict__ qc,
    float* __restrict__ ido, float* __restrict__ dsum, int M, int HW) {
    __shared__ short Fh[64 * 72];
    __shared__ short Fl[64 * 72];
    __shared__ float S[64 * 65];
    __shared__ int   KI[64];
    __shared__ float wsum[4];

    const int tid = threadIdx.x;
    const int lane = tid & 63, wv = tid >> 6;
    const int quad = lane >> 4, l16 = lane & 15;
    const int R0 = blockIdx.x * 64;

    {
        int row = tid >> 2;
        int k0 = (tid & 3) * 16;
        const float* sp = f + (long)(R0 + row) * 64 + k0;
        unsigned hw[8], lw[8];
#pragma unroll
        for (int i = 0; i < 4; ++i) {
            float4 p = *(const float4*)(sp + 4 * i);
            cvt_split2(p.x, p.y, hw[2 * i], lw[2 * i]);
            cvt_split2(p.z, p.w, hw[2 * i + 1], lw[2 * i + 1]);
        }
        short* dh = &Fh[row * 72 + k0];
        short* dl = &Fl[row * 72 + k0];
        *(uint4*)(dh)     = make_uint4(hw[0], hw[1], hw[2], hw[3]);
        *(uint4*)(dh + 8) = make_uint4(hw[4], hw[5], hw[6], hw[7]);
        *(uint4*)(dl)     = make_uint4(lw[0], lw[1], lw[2], lw[3]);
        *(uint4*)(dl + 8) = make_uint4(lw[4], lw[5], lw[6], lw[7]);
    }
    __syncthreads();

    const int arow = (wv * 16 + l16) * 72;
    bf16x8 Ah0 = *(const bf16x8*)&Fh[arow + quad * 8];
    bf16x8 Ah1 = *(const bf16x8*)&Fh[arow + 32 + quad * 8];
    bf16x8 Al0 = *(const bf16x8*)&Fl[arow + quad * 8];
    bf16x8 Al1 = *(const bf16x8*)&Fl[arow + 32 + quad * 8];

    float bestv[4];
    int   besti[4];
#pragma unroll
    for (int r = 0; r < 4; ++r) { bestv[r] = 3.4e38f; besti[r] = 0; }

    const short* ETlo = ET + 32768;
#pragma unroll 2
    for (int j = 0; j < 32; ++j) {
        const int nb = (j * 16 + l16) * 64 + quad * 8;
        bf16x8 Bh0 = *(const bf16x8*)(ET + nb);
        bf16x8 Bh1 = *(const bf16x8*)(ET + nb + 32);
        bf16x8 Bl0 = *(const bf16x8*)(ETlo + nb);
        bf16x8 Bl1 = *(const bf16x8*)(ETlo + nb + 32);
        f32x4 acc = f32x4{0.f, 0.f, 0.f, 0.f};
        acc = __builtin_amdgcn_mfma_f32_16x16x32_bf16(Ah0, Bh0, acc, 0, 0, 0);
        acc = __builtin_amdgcn_mfma_f32_16x16x32_bf16(Ah1, Bh1, acc, 0, 0, 0);
        acc = __builtin_amdgcn_mfma_f32_16x16x32_bf16(Al0, Bh0, acc, 0, 0, 0);
        acc = __builtin_amdgcn_mfma_f32_16x16x32_bf16(Al1, Bh1, acc, 0, 0, 0);
        acc = __builtin_amdgcn_mfma_f32_16x16x32_bf16(Ah0, Bl0, acc, 0, 0, 0);
        acc = __builtin_amdgcn_mfma_f32_16x16x32_bf16(Ah1, Bl1, acc, 0, 0, 0);
        float en = enorm[j * 16 + l16];
        int   ni = j * 16 + l16;
#pragma unroll
        for (int r = 0; r < 4; ++r) {
            float s = fmaf(-2.f, acc[r], en);
            if (s < bestv[r]) { bestv[r] = s; besti[r] = ni; }
        }
    }
#pragma unroll
    for (int m = 1; m < 16; m <<= 1) {
#pragma unroll
        for (int r = 0; r < 4; ++r) {
            float ov = __shfl_xor(bestv[r], m);
            int   oi = __shfl_xor(besti[r], m);
            if (ov < bestv[r] || (ov == bestv[r] && oi < besti[r])) {
                bestv[r] = ov; besti[r] = oi;
            }
        }
    }
    if (l16 == 0) {
#pragma unroll
        for (int r = 0; r < 4; ++r) KI[wv * 16 + quad * 4 + r] = besti[r];
    }
    __syncthreads();

    float ddacc = 0.f;
#pragma unroll 1
    for (int r16 = 0; r16 < 16; ++r16) {
        int row = wv * 16 + r16;
        int k = KI[row];
        float ev = embed[lane * 512 + k];
        float fv = f[(long)(R0 + row) * 64 + lane];
        long qi = (long)(R0 + row) * 64 + lane;
        if (qn) qn[qi] = ev;
        qnb[qi] = (short)bf16_rne(ev);
        S[row * 65 + lane] = ev;
        float dq = ev - fv;
        ddacc = fmaf(dq, dq, ddacc);
        if (lane == 0) ido[R0 + row] = (float)k;
    }
#pragma unroll
    for (int off = 1; off < 64; off <<= 1) ddacc += __shfl_xor(ddacc, off);
    if (lane == 0) wsum[wv] = ddacc;
    __syncthreads();
    if (tid == 0)
        atomicAdd(dsum, wsum[0] + wsum[1] + wsum[2] + wsum[3]);

    int nn = R0 / HW;
    int rem0 = R0 - nn * HW;
    int px = tid & 63;
    int cg = tid >> 6;
#pragma unroll
    for (int it = 0; it < 16; ++it) {
        int c = cg + 4 * it;
        qc[((long)nn * 64 + c) * HW + rem0 + px] = S[px * 65 + c];
    }
}

// ---------------------------------------------------------------------------
// ECAT concat: [DECT fp32 64ch | T1B split-bf16 reconstructed 128ch] -> fp32
// ---------------------------------------------------------------------------
__global__ void concat_rec_kernel(const float* __restrict__ a, const short* __restrict__ bh,
                                  float* __restrict__ o, int M) {
    const long PLB = 8388608L;   // 16*64*64*128
    int idx = blockIdx.x * TPB + threadIdx.x;
    if (idx >= M * 48) return;
    int row = idx / 48;
    int c4  = (idx - row * 48) * 4;
    float4 v;
    if (c4 < 64) v = *(const float4*)(a + (long)row * 64 + c4);
    else {
        int cc = c4 - 64;
        uint2 h = *(const uint2*)(bh + (long)row * 128 + cc);
        uint2 l = *(const uint2*)(bh + PLB + (long)row * 128 + cc);
        v.x = __uint_as_float(h.x << 16)         + __uint_as_float(l.x << 16);
        v.y = __uint_as_float(h.x & 0xFFFF0000u) + __uint_as_float(l.x & 0xFFFF0000u);
        v.z = __uint_as_float(h.y << 16)         + __uint_as_float(l.y << 16);
        v.w = __uint_as_float(h.y & 0xFFFF0000u) + __uint_as_float(l.y & 0xFFFF0000u);
    }
    *(float4*)(o + (long)row * 192 + c4) = v;
}

// ---------------------------------------------------------------------------
// QCAT concat (plain bf16): ch0-63 = cvt(UPT fp32), ch64-127 = QBNB copy.
// ---------------------------------------------------------------------------
__global__ void concat_qcat_kernel(const float* __restrict__ a, const short* __restrict__ qh,
                                   short* __restrict__ o, int M) {
    int idx = blockIdx.x * TPB + threadIdx.x;
    if (idx >= M * 32) return;
    int row = idx / 32;
    int c4  = (idx - row * 32) * 4;
    uint2 w;
    if (c4 < 64) {
        float4 v = *(const float4*)(a + (long)row * 64 + c4);
        w = make_uint2(cvt_pk(v.x, v.y), cvt_pk(v.z, v.w));
    } else {
        w = *(const uint2*)(qh + (long)row * 64 + (c4 - 64));
    }
    *(uint2*)(o + (long)row * 128 + c4) = w;
}

// ---------------------------------------------------------------------------
__global__ void loss_kernel(const float* __restrict__ sums, float* __restrict__ out) {
    out[0] = sums[0] * (1.f / (16384.f * 64.f)) + sums[1] * (1.f / (65536.f * 64.f));
}

// ---------------------------------------------------------------------------
extern "C" void kernel_launch(void* const* d_in, const int* in_sizes, int n_in,
                              void* d_out, int out_size, void* d_ws, size_t ws_size,
                              hipStream_t stream) {
    const float* x   = (const float*)d_in[0];
    const float* wb1 = (const float*)d_in[1];  const float* bb1 = (const float*)d_in[2];
    const float* wb2 = (const float*)d_in[3];  const float* bb2 = (const float*)d_in[4];
    const float* wt1 = (const float*)d_in[5];  const float* bt1 = (const float*)d_in[6];
    const float* wqt = (const float*)d_in[7];  const float* bqt = (const float*)d_in[8];
    const float* embed_t = (const float*)d_in[9];
    const float* wdt = (const float*)d_in[10]; const float* bdt = (const float*)d_in[11];
    const float* wqb = (const float*)d_in[12]; const float* bqb = (const float*)d_in[13];
    const float* embed_b = (const float*)d_in[14];
    const float* wup = (const float*)d_in[15]; const float* bup = (const float*)d_in[16];
    const float* wd1 = (const float*)d_in[17]; const float* bd1 = (const float*)d_in[18];
    const float* wd2 = (const float*)d_in[19]; const float* bd2 = (const float*)d_in[20];
    float* out = (float*)d_out;
    float* ws  = (float*)d_ws;

    float* O_XHAT = out;
    float* O_QT   = out + 3145728;
    float* O_QB   = out + 4194304;
    float* O_LOSS = out + 8388608;
    float* O_IDT  = out + 8388609;
    float* O_IDB  = out + 8404993;

    // ws layout (float-slot offsets)
    float* W_WB1  = ws + 0;                    // 6144 fp32 (conv1)
    short* WB_WD2 = (short*)(ws + 16384);      // 16384 sh
    short* ET_T   = (short*)(ws + 32768);      // 65536 sh
    short* ET_B   = (short*)(ws + 65536);      // 65536 sh
    short* WB_WQT = (short*)(ws + 98304);      // 16384 sh (split 1x1 128->64)
    float* W_WDT  = ws + 540672;               // 65536 fp32 (exact convT 64->64)
    float* W_WQB  = ws + 606208;               // 12288 fp32 (exact 1x1 192->64)
    float* EN_T  = ws + 818176;
    float* EN_B  = ws + 818688;
    float* SUMS  = ws + 819200;
    short* T1B   = (short*)(ws + 1048576);     // split [2][16,64,64,128]
    const long BIG = 9437184;
    short* T0B   = (short*)(ws + BIG);         // split [2][16,128,128,128]
    short* T2B   = (short*)(ws + BIG);         // split [2][16,32,32,128] (T0B dead)
    float* QT    = ws + BIG + 2097152;         // fp32 [16384,64]
    float* QTN   = ws + BIG + 3145728;         // fp32 quant_t rows (for wdt)
    short* QTNB  = (short*)(ws + BIG + 4194304);  // plain bf16 (for wup)
    float* DECT  = ws + BIG + 4718592;         // fp32 [16,64,64,64]
    float* ECAT  = ws + BIG + 8912896;         // fp32 [16,64,64,192]
    float* QB    = ws + BIG + 21495808;        // fp32 [65536,64]
    short* QBNB  = (short*)(ws + BIG + 25690112); // plain bf16 [65536,64]
    float* UPT   = ws + BIG + 4718592;         // fp32, reuses DECT
    short* QCATB = (short*)(ws + BIG + 8912896);  // plain bf16, reuses ECAT
    short* HBUFB = (short*)(ws + BIG + 16777216); // plain bf16 [16,128,128,64]
    short* WB_BF2 = (short*)(ws + 42991616);
    short* WB_BT1 = (short*)(ws + 43253760);
    short* WB_BD1 = (short*)(ws + 43515904);
    short* WB_BUP = (short*)(ws + 43646976);

    auto wt_launch = [&](const float* src, float* dst, int cin, int cout, int taps, int iohw) {
        int tot = cin * cout * taps;
        wtrans_kernel<<<(tot + TPB - 1) / TPB, TPB, 0, stream>>>(src, dst, cin, cout, taps, iohw);
    };
    auto wtb_launch = [&](const float* src, short* dst, int cin, int cout, int taps, int iohw) {
        int tot = cin * cout * taps;
        wtrans_bf16_kernel<<<(tot + TPB - 1) / TPB, TPB, 0, stream>>>(src, dst, cin, cout, taps, iohw, tot);
    };
    wt_launch(wb1, W_WB1, 3, 128, 16, 0);
    wt_launch(wdt, W_WDT, 64, 64, 16, 1);
    wt_launch(wqb, W_WQB, 192, 64, 1, 0);
    wtrans_wd2_kernel<<<64, TPB, 0, stream>>>(wd2, WB_WD2);
    wtb_launch(wb2, WB_BF2, 128, 128, 16, 0);
    wtb_launch(wt1, WB_BT1, 128, 128, 16, 0);
    wtb_launch(wqt, WB_WQT, 128, 64, 1, 0);
    wtb_launch(wd1, WB_BD1, 128, 64, 16, 1);
    wtb_launch(wup, WB_BUP, 64, 64, 16, 1);
    enorm_kernel<<<4, TPB, 0, stream>>>(embed_t, embed_b, EN_T, EN_B);
    etrans_kernel<<<256, TPB, 0, stream>>>(embed_t, embed_b, ET_T, ET_B);
    hipError_t e0 = hipMemsetAsync((void*)SUMS, 0, 2 * sizeof(float), stream);
    (void)e0;

    // ----- encode -----
    conv1_kernel<<<4096, TPB, 0, stream>>>(x, W_WB1, bb1, T0B);
    // conv2: split in/out, KR=32, NSP=1 (empirically best: R9 146us vs R11 161)
    mfma_conv<0, 128, 128, 1, 1, 128, 128, 64, 64, 2, 1, 3, 32, 1>
        <<<512, TPB, 0, stream>>>(T0B, WB_BF2, bb2, nullptr, T1B);
    // conv3: split in/out, NSP=2 with same-XCD co-pairing (grid 256)
    mfma_conv<0, 128, 128, 1, 1, 64, 64, 32, 32, 4, 1, 3, 32, 2>
        <<<256, TPB, 0, stream>>>(T1B, WB_BT1, bt1, nullptr, T2B);
    // wqt 1x1: split MFMA, fp32 out
    mfma_conv<2, 128, 64, 1, 0, 32, 32, 32, 32, 4, 1, 0, 64, 1>
        <<<128, TPB, 0, stream>>>(T2B, WB_WQT, bqt, QT, nullptr);
    quantize_mfma<<<256, TPB, 0, stream>>>(QT, ET_T, embed_t, EN_T, QTN, QTNB,
                                           O_QT, O_IDT, SUMS, 16384, 1024);
    // wdt: fp32 exact (id_b-critical)
    conv_gemm<1, 64, 64, 32, 0, 32, 32, 64, 64><<<2048, TPB, 0, stream>>>(QTN, W_WDT, bdt, DECT);
    concat_rec_kernel<<<12288, TPB, 0, stream>>>(DECT, T1B, ECAT, 65536);
    // wqb: fp32 exact (id_b-critical)
    conv_gemm<2, 192, 64, 64, 0, 64, 64, 64, 64><<<1024, TPB, 0, stream>>>(ECAT, W_WQB, bqb, QB);
    quantize_mfma<<<1024, TPB, 0, stream>>>(QB, ET_B, embed_b, EN_B, nullptr, QBNB,
                                            O_QB, O_IDB, SUMS + 1, 65536, 4096);
    // ----- decode -----
    // wup: plain bf16 in (QTNB), KR=64, fp32 out
    mfma_conv<1, 64, 64, 0, 0, 32, 32, 64, 64, 4, 1, 0, 64, 1>
        <<<512, TPB, 0, stream>>>(QTNB, WB_BUP, bup, UPT, nullptr);
    concat_qcat_kernel<<<8192, TPB, 0, stream>>>(UPT, QBNB, QCATB, 65536);
    // dec1: plain bf16 in, KR=64, plain bf16 out + ReLU
    mfma_conv<1, 128, 64, 0, 1, 64, 64, 128, 128, 2, 1, 2, 64, 1>
        <<<2048, TPB, 0, stream>>>(QCATB, WB_BD1, bd1, nullptr, HBUFB);
    convt_final_mfma<<<2048, TPB, 0, stream>>>(HBUFB, WB_WD2, bd2, O_XHAT);
    loss_kernel<<<1, 1, 0, stream>>>(SUMS, O_LOSS);

    (void)in_sizes; (void)n_in; (void)out_size; (void)ws_size;
}